// Round 8
// baseline (6744.482 us; speedup 1.0000x reference)
//
#include <hip/hip_runtime.h>
#include <hip/hip_bf16.h>
#include <math.h>

#define NN 16384
#define NE 262144
#define NB 64
#define FD 32
#define NT 8
#define NL 3
#define NH 128
#define EPSV 1e-5f

typedef unsigned short u16;
typedef unsigned int u32;
typedef long long i64;

static __device__ __forceinline__ float us2f(u16 u){
  union { u32 i; float f; } z; z.i = ((u32)u) << 16; return z.f;
}
static __device__ __forceinline__ u32 encf(float v){
  u32 u = __float_as_uint(v);
  return (u & 0x80000000u) ? ~u : (u | 0x80000000u);
}
static __device__ __forceinline__ float decf(u32 e){
  return __uint_as_float((e & 0x80000000u) ? (e & 0x7FFFFFFFu) : ~e);
}

__global__ void k_diag(float* out, float v){
  int i = threadIdx.x;
  if (i < 128) out[i] = v;
}

// ---------- weight dtype detect ----------
__global__ __launch_bounds__(256) void k_detect(const u16* __restrict__ ne, int* __restrict__ flags){
  __shared__ float red[256];
  const int tid = threadIdx.x;
  float m = 0.f;
  for (int i=tid; i<1024; i+=256) m = fmaxf(m, fabsf(us2f(ne[i])));
  red[tid]=m; __syncthreads();
  for (int off=128; off>0; off>>=1){ if (tid<off) red[tid]=fmaxf(red[tid],red[tid+off]); __syncthreads(); }
  if (tid==0) flags[0] = (red[0] > 100.f) ? 1 : 0;
}

// ---------- int width detect ----------
__global__ __launch_bounds__(256) void k_det_i64(const int* __restrict__ ei_raw, int* __restrict__ flags){
  __shared__ int red[256];
  const int tid = threadIdx.x;
  int i = blockIdx.x*256 + tid;
  int c = (i < NE && ei_raw[2*i+1] == 0) ? 1 : 0;
  red[tid]=c; __syncthreads();
  for (int off=128; off>0; off>>=1){ if (tid<off) red[tid]+=red[tid+off]; __syncthreads(); }
  if (tid==0) atomicAdd(&flags[4], red[0]);
}
__global__ void k_set_i64(int* __restrict__ flags){
  flags[2] = (flags[4] > NE/4) ? 1 : 0;
}

struct IJobs { const void* src[4]; int* dst[4]; int cnt[4]; };
__global__ __launch_bounds__(256) void k_cvt_int(IJobs jb, const int* __restrict__ flags, int total){
  int i = blockIdx.x*256 + threadIdx.x;
  if (i >= total) return;
  const int m = flags[2];
  int a = 0, off = i;
  while (off >= jb.cnt[a]){ off -= jb.cnt[a]; a++; }
  int v = m ? (int)((const i64*)jb.src[a])[off] : ((const int*)jb.src[a])[off];
  jb.dst[a][off] = v;
}

struct Jobs { const void* src[20]; float* dst[20]; int cnt[20]; };
__global__ __launch_bounds__(256) void k_cvt(Jobs jb, const int* __restrict__ flags, int total){
  int i = blockIdx.x*256 + threadIdx.x;
  if (i >= total) return;
  const int m = flags[0];
  int a = 0, off = i;
  while (off >= jb.cnt[a]){ off -= jb.cnt[a]; a++; }
  float v = m ? ((const float*)jb.src[a])[off]
              : us2f(((const u16*)jb.src[a])[off]);
  jb.dst[a][off] = v;
}

// ---------------- degree ----------------
__global__ void k_count(const int* __restrict__ dst, int* __restrict__ deg){
  int e = blockIdx.x*256 + threadIdx.x;
  if (e < NE) atomicAdd(&deg[dst[e]], 1);
}

// ---------------- avg log (f64, one block) ----------------
__global__ __launch_bounds__(256) void k_logsumF(const int* __restrict__ deg, double* __restrict__ lsum){
  __shared__ double red[256];
  const int tid = threadIdx.x;
  double s = 0.0;
  for (int n=tid; n<NN; n+=256) s += log((double)deg[n] + 1.0);
  red[tid]=s; __syncthreads();
  for (int off=128; off>0; off>>=1){ if (tid<off) red[tid]+=red[tid+off]; __syncthreads(); }
  if (tid==0) *lsum = red[0] / (double)NN;
}

__global__ void k_scalersF(const int* __restrict__ deg, const double* __restrict__ lsum,
                           float* __restrict__ amp, float* __restrict__ attn, float* __restrict__ invc){
  int n = blockIdx.x*256 + threadIdx.x;
  if (n >= NN) return;
  float avg = (float)(*lsum);
  int d = deg[n]; int dc = d > 0 ? d : 1;
  float la = logf((float)dc + 1.0f);
  amp[n] = la/avg; attn[n] = avg/la; invc[n] = 1.0f/(float)dc;
}

// ---------------- embedding ----------------
__global__ void k_embed(const int* __restrict__ x, const float* __restrict__ emb,
                        float* __restrict__ h){
  int i = blockIdx.x*256 + threadIdx.x;
  if (i < NN*FD){
    int n = i>>5, f = i&31;
    h[i] = emb[x[n]*FD + f];
  }
}

// ---------------- per-layer edge-attr encoding: eenc[a][f2] ----------------
__global__ void k_eenc(const float* __restrict__ ee, const float* __restrict__ Wee,
                       const float* __restrict__ bee, float* __restrict__ eenc, int l){
  int i = blockIdx.x*256 + threadIdx.x;
  if (i >= 16*FD) return;
  int a = i>>5, f2 = i&31;
  float acc = bee[l*FD + f2];
  for (int c2=0; c2<16; c2++)
    acc = fmaf(ee[a*16+c2], Wee[(l*16+c2)*FD+f2], acc);
  eenc[i] = acc;
}

// ---------------- zero accumulators ----------------
__global__ void k_zeroacc(float* __restrict__ sumb, float* __restrict__ sqb,
                          u32* __restrict__ mnb, u32* __restrict__ mxb){
  int i = blockIdx.x*256 + threadIdx.x;
  if (i < NN*FD){ sumb[i]=0.f; sqb[i]=0.f; mnb[i]=0xFFFFFFFFu; mxb[i]=0u; }
}

// ---------------- edge kernel: direct 96-FMA message, LDS-staged weights ----------------
__global__ __launch_bounds__(256) void k_edgeF(
    const int* __restrict__ ei, const int* __restrict__ ea,
    const float* __restrict__ h, const float* __restrict__ eenc,
    const float* __restrict__ Wpre, const float* __restrict__ bpre,
    float* __restrict__ sumb, float* __restrict__ sqb,
    u32* __restrict__ mnb, u32* __restrict__ mxb, int l, int tt)
{
  __shared__ float Wl[96*FD];
  __shared__ float el[16*FD];
  const int tid = threadIdx.x;
  const float* W = Wpre + (size_t)((l*NT+tt)*96)*FD;
  for (int i=tid; i<96*FD; i+=256) Wl[i] = W[i];
  for (int i=tid; i<16*FD; i+=256) el[i] = eenc[i];
  __syncthreads();
  const int e = blockIdx.x*8 + (tid>>5);
  const int f = tid&31;
  const int s = ei[e];
  const int d = ei[NE+e];
  const int a = ea[e];
  float v = bpre[(l*NT+tt)*FD + f];
  for (int c=0;c<FD;c++) v = fmaf(h[d*FD+c],  Wl[c*FD+f], v);
  for (int c=0;c<FD;c++) v = fmaf(h[s*FD+c],  Wl[(32+c)*FD+f], v);
  for (int c=0;c<FD;c++) v = fmaf(el[a*FD+c], Wl[(64+c)*FD+f], v);
  const int idx = d*FD + f;
  atomicAdd(&sumb[idx], v);
  atomicAdd(&sqb[idx], v*v);
  u32 ev = encf(v);
  atomicMin(&mnb[idx], ev);
  atomicMax(&mxb[idx], ev);
}

// ---------------- post-MLP: explicit 416-row loop ----------------
__global__ __launch_bounds__(256) void k_tailF(
    const float* __restrict__ sumb, const float* __restrict__ sqb,
    const u32* __restrict__ mnb, const u32* __restrict__ mxb,
    const float* __restrict__ h, const int* __restrict__ deg,
    const float* __restrict__ amp, const float* __restrict__ attn, const float* __restrict__ invc,
    const float* __restrict__ Wpost, const float* __restrict__ bpost,
    float* __restrict__ outbuf, int l, int tt)
{
  int i = blockIdx.x*256 + threadIdx.x;
  if (i >= NN*4) return;
  const int n = i>>2, j = i&3;
  const int dg = deg[n];
  const float ic = invc[n], av = amp[n], at_ = attn[n];
  const float* W = Wpost + (size_t)((l*NT+tt)*416)*4;
  float acc = bpost[(l*NT+tt)*4 + j];
  for (int c=0; c<416; c++){
    float x;
    if (c < 32){
      x = h[n*FD + c];
    } else {
      int cc = c - 32;
      int grp = cc >> 7;        // 0 plain, 1 *amp, 2 *att
      int k = cc & 127;
      int ag = k >> 5, kk = k & 31;
      int idx = n*FD + kk;
      float base;
      if (ag == 0){ base = sumb[idx]*ic; }
      else if (ag == 1){ base = (dg>0) ? decf(mnb[idx]) : 0.f; }
      else if (ag == 2){ base = (dg>0) ? decf(mxb[idx]) : 0.f; }
      else { float mean = sumb[idx]*ic;
             base = sqrtf(fmaxf(sqb[idx]*ic - mean*mean, 0.f) + EPSV); }
      x = base * (grp==0 ? 1.f : (grp==1 ? av : at_));
    }
    acc = fmaf(x, W[c*4 + j], acc);
  }
  outbuf[n*FD + tt*4 + j] = acc;
}

// ---------------- tower-mixing linear ----------------
__global__ void k_lin(const float* __restrict__ outbuf, const float* __restrict__ Wlin,
                      const float* __restrict__ blin, float* __restrict__ z, int l){
  int i = blockIdx.x*256 + threadIdx.x;
  if (i >= NN*FD) return;
  const int n = i>>5, f = i&31;
  float zv = blin[l*FD + f];
  for (int dp=0; dp<FD; dp++)
    zv = fmaf(outbuf[n*FD+dp], Wlin[(l*FD+dp)*FD + f], zv);
  z[i] = zv;
}

// ---------------- BN: two-pass f64 ----------------
__global__ __launch_bounds__(256) void k_sum1(const float* __restrict__ z, double* __restrict__ st){
  const int tid = threadIdx.x;
  const int f = tid&31, rg = tid>>5;
  double s = 0.0;
  for (int n = blockIdx.x*8 + rg; n < NN; n += 512) s += (double)z[n*FD+f];
  __shared__ double l1[256];
  l1[tid]=s; __syncthreads();
  if (rg<4) l1[tid]+=l1[tid+128]; __syncthreads();
  if (rg<2) l1[tid]+=l1[tid+64];  __syncthreads();
  if (rg<1) atomicAdd(&st[f], l1[tid]+l1[tid+32]);
}
__global__ __launch_bounds__(256) void k_sum2(const float* __restrict__ z, const double* __restrict__ st,
                                              double* __restrict__ st2){
  const int tid = threadIdx.x;
  const int f = tid&31, rg = tid>>5;
  const double mu = st[f] * (1.0/(double)NN);
  double s = 0.0;
  for (int n = blockIdx.x*8 + rg; n < NN; n += 512){
    double d = (double)z[n*FD+f] - mu; s += d*d;
  }
  __shared__ double l1[256];
  l1[tid]=s; __syncthreads();
  if (rg<4) l1[tid]+=l1[tid+128]; __syncthreads();
  if (rg<2) l1[tid]+=l1[tid+64];  __syncthreads();
  if (rg<1) atomicAdd(&st2[f], l1[tid]+l1[tid+32]);
}
__global__ void k_bnF(const float* __restrict__ z, const double* __restrict__ st,
                      const double* __restrict__ st2,
                      const float* __restrict__ bng, const float* __restrict__ bnb,
                      float* __restrict__ h, int l){
  int i = blockIdx.x*256 + threadIdx.x;
  if (i >= NN*FD) return;
  int f = i&31;
  float mu  = (float)(st[f]  * (1.0/(double)NN));
  float var = (float)(st2[f] * (1.0/(double)NN));
  float sc = bng[l*FD+f]*rsqrtf(var+EPSV);
  float v = (z[i]-mu)*sc + bnb[l*FD+f];
  h[i] = fmaxf(v, 0.f);
}

// ---------------- pooling: block-per-graph scan ----------------
__global__ __launch_bounds__(256) void k_poolF(const float* __restrict__ h, const int* __restrict__ batch,
                                               float* __restrict__ g){
  __shared__ float acc[8][FD];
  const int b = blockIdx.x;
  const int tid = threadIdx.x;
  const int f = tid&31, rg = tid>>5;
  float s = 0.f;
  for (int n=rg; n<NN; n+=8)
    if (batch[n] == b) s += h[n*FD+f];
  acc[rg][f] = s; __syncthreads();
  if (rg == 0){
    float t = 0.f;
    for (int r=0;r<8;r++) t += acc[r][f];
    g[b*FD+f] = t;
  }
}

// ---------------- head: per-feature serial, f64 BN, f32 OUTPUT ----------------
__global__ __launch_bounds__(128) void k_headF(
    const float* __restrict__ gpool,
    const float* __restrict__ Wm0, const float* __restrict__ bm0,
    const float* __restrict__ Wmh, const float* __restrict__ bmh,
    const float* __restrict__ bnmg, const float* __restrict__ bnmb,
    const float* __restrict__ Wf, const float* __restrict__ bfv,
    float* __restrict__ out)
{
  __shared__ float A[NB*NH];
  __shared__ float gl[NB*FD];
  const int hh = threadIdx.x;     // 0..127
  for (int i=hh; i<NB*FD; i+=128) gl[i] = gpool[i];
  __syncthreads();
  for (int b=0;b<NB;b++){
    float acc = bm0[hh];
    for (int c=0;c<FD;c++) acc = fmaf(gl[b*FD+c], Wm0[c*NH+hh], acc);
    A[b*NH+hh] = acc;
  }
  {
    double s=0.0; for (int b=0;b<NB;b++) s += (double)A[b*NH+hh];
    double mu = s/(double)NB;
    double v=0.0; for (int b=0;b<NB;b++){ double d=(double)A[b*NH+hh]-mu; v+=d*d; }
    v /= (double)NB;
    float sc = bnmg[hh]*rsqrtf((float)v+EPSV);
    float sh = bnmb[hh]-(float)mu*sc;
    for (int b=0;b<NB;b++) A[b*NH+hh] = fmaxf(A[b*NH+hh]*sc+sh, 0.f);
  }
  __syncthreads();
  for (int i=0;i<2;i++){
    float col[NB];
    for (int b=0;b<NB;b++){
      float acc = bmh[i*NH+hh];
      for (int c=0;c<NH;c++) acc = fmaf(A[b*NH+c], Wmh[(i*NH+c)*NH+hh], acc);
      col[b] = acc;
    }
    __syncthreads();
    for (int b=0;b<NB;b++) A[b*NH+hh] = col[b];
    double s=0.0; for (int b=0;b<NB;b++) s += (double)A[b*NH+hh];
    double mu = s/(double)NB;
    double v=0.0; for (int b=0;b<NB;b++){ double d=(double)A[b*NH+hh]-mu; v+=d*d; }
    v /= (double)NB;
    float sc = bnmg[(i+1)*NH+hh]*rsqrtf((float)v+EPSV);
    float sh = bnmb[(i+1)*NH+hh]-(float)mu*sc;
    for (int b=0;b<NB;b++) A[b*NH+hh] = fmaxf(A[b*NH+hh]*sc+sh, 0.f);
    __syncthreads();
  }
  if (hh < NB){
    float acc = bfv[0];
    for (int c=0;c<NH;c++) acc = fmaf(A[hh*NH+c], Wf[c], acc);
    out[NB+hh] = acc;                         // logits (f32)
    out[hh]    = 1.f/(1.f+expf(-acc));        // sigmoid (f32)
  }
}

extern "C" void kernel_launch(void* const* d_in, const int* in_sizes, int n_in,
                              void* d_out, int out_size, void* d_ws, size_t ws_size,
                              hipStream_t stream)
{
  float* out = (float*)d_out;

  static const int EXP_SZ[24] = {16384, 524288, 262144, 16384, 1024, 256, 1536, 96,
                                 73728, 768, 39936, 96, 3072, 96, 96, 96,
                                 4096, 128, 32768, 256, 384, 384, 128, 1};
  int bad = -1;
  if (n_in != 24) bad = 24;
  else for (int i=0;i<24;i++){ if (in_sizes[i] != EXP_SZ[i]){ bad = i; break; } }
  if (bad >= 0){
    k_diag<<<1, 128, 0, stream>>>(out, 512.0f + 8.0f*(float)bad);
    return;
  }

  char* p = (char*)d_ws;
  auto carve = [&](size_t bytes)->char*{ char* r = p; p += (bytes + 255) & ~(size_t)255; return r; };
  int*    flags = (int*)carve(64);
  int*    deg   = (int*)carve((size_t)NN*4);
  float*  h     = (float*)carve((size_t)NN*FD*4);
  float*  z     = (float*)carve((size_t)NN*FD*4);
  float*  outbuf= (float*)carve((size_t)NN*FD*4);
  float*  sumb  = (float*)carve((size_t)NN*FD*4);
  float*  sqb   = (float*)carve((size_t)NN*FD*4);
  u32*    mnb   = (u32*)carve((size_t)NN*FD*4);
  u32*    mxb   = (u32*)carve((size_t)NN*FD*4);
  float*  eenc  = (float*)carve(16*FD*4);
  float*  amp   = (float*)carve((size_t)NN*4);
  float*  attn  = (float*)carve((size_t)NN*4);
  float*  invc  = (float*)carve((size_t)NN*4);
  double* lsum  = (double*)carve(8);
  double* st1   = (double*)carve(32*8);
  double* st2   = (double*)carve(32*8);
  float*  gp    = (float*)carve((size_t)NB*FD*4);
  int*    cx    = (int*)carve((size_t)NN*4);
  int*    cei   = (int*)carve((size_t)2*NE*4);
  int*    cea   = (int*)carve((size_t)NE*4);
  int*    cbatch= (int*)carve((size_t)NN*4);

  Jobs jb;
  float* wptr[24];
  int total = 0;
  {
    float* cur = (float*)carve(700*1024);
    for (int i=4; i<24; i++){
      jb.src[i-4] = d_in[i];
      jb.dst[i-4] = cur;
      jb.cnt[i-4] = in_sizes[i];
      wptr[i] = cur;
      cur += in_sizes[i];
      total += in_sizes[i];
    }
  }
  const size_t need = (size_t)(p - (char*)d_ws);
  if (ws_size < need){
    k_diag<<<1, 128, 0, stream>>>(out, -2000.0f - (float)(ws_size >> 20));
    return;
  }

  IJobs ij;
  ij.src[0]=d_in[0]; ij.dst[0]=cx;     ij.cnt[0]=NN;
  ij.src[1]=d_in[1]; ij.dst[1]=cei;    ij.cnt[1]=2*NE;
  ij.src[2]=d_in[2]; ij.dst[2]=cea;    ij.cnt[2]=NE;
  ij.src[3]=d_in[3]; ij.dst[3]=cbatch; ij.cnt[3]=NN;
  const int itotal = NN + 2*NE + NE + NN;

  const float* ne_f   = wptr[4];
  const float* ee_f   = wptr[5];
  const float* Wee_f  = wptr[6];
  const float* bee_f  = wptr[7];
  const float* Wpre_f = wptr[8];
  const float* bpre_f = wptr[9];
  const float* Wpost_f= wptr[10];
  const float* bpost_f= wptr[11];
  const float* Wlin_f = wptr[12];
  const float* blin_f = wptr[13];
  const float* bng_f  = wptr[14];
  const float* bnb_f  = wptr[15];
  const float* Wm0_f  = wptr[16];
  const float* bm0_f  = wptr[17];
  const float* Wmh_f  = wptr[18];
  const float* bmh_f  = wptr[19];
  const float* bnmg_f = wptr[20];
  const float* bnmb_f = wptr[21];
  const float* Wf_f   = wptr[22];
  const float* bf_f   = wptr[23];

  hipMemsetAsync(flags, 0, 64, stream);
  hipMemsetAsync(deg, 0, (size_t)NN*4, stream);

  k_detect<<<1, 256, 0, stream>>>((const u16*)d_in[4], flags);
  k_det_i64<<<NE/256, 256, 0, stream>>>((const int*)d_in[1], flags);
  k_set_i64<<<1, 1, 0, stream>>>(flags);
  k_cvt_int<<<(itotal+255)/256, 256, 0, stream>>>(ij, flags, itotal);
  k_cvt<<<(total+255)/256, 256, 0, stream>>>(jb, flags, total);

  k_count<<<NE/256, 256, 0, stream>>>(cei+NE, deg);
  k_logsumF<<<1, 256, 0, stream>>>(deg, lsum);
  k_scalersF<<<NN/256, 256, 0, stream>>>(deg, lsum, amp, attn, invc);
  k_embed<<<NN*FD/256, 256, 0, stream>>>(cx, ne_f, h);

  for (int l=0; l<NL; l++){
    k_eenc<<<2, 256, 0, stream>>>(ee_f, Wee_f, bee_f, eenc, l);
    for (int tt=0; tt<NT; tt++){
      k_zeroacc<<<NN*FD/256, 256, 0, stream>>>(sumb, sqb, mnb, mxb);
      k_edgeF<<<NE/8, 256, 0, stream>>>(cei, cea, h, eenc, Wpre_f, bpre_f,
                                        sumb, sqb, mnb, mxb, l, tt);
      k_tailF<<<NN*4/256, 256, 0, stream>>>(sumb, sqb, mnb, mxb, h, deg, amp, attn, invc,
                                            Wpost_f, bpost_f, outbuf, l, tt);
    }
    k_lin<<<NN*FD/256, 256, 0, stream>>>(outbuf, Wlin_f, blin_f, z, l);
    hipMemsetAsync(st1, 0, 32*8, stream);
    hipMemsetAsync(st2, 0, 32*8, stream);
    k_sum1<<<64, 256, 0, stream>>>(z, st1);
    k_sum2<<<64, 256, 0, stream>>>(z, st1, st2);
    k_bnF<<<NN*FD/256, 256, 0, stream>>>(z, st1, st2, bng_f, bnb_f, h, l);
  }

  k_poolF<<<NB, 256, 0, stream>>>(h, cbatch, gp);
  k_headF<<<1, 128, 0, stream>>>(gp, Wm0_f, bm0_f, Wmh_f, bmh_f, bnmg_f, bnmb_f, Wf_f, bf_f, out);
}

// Round 9
// 1197.501 us; speedup vs baseline: 5.6321x; 5.6321x over previous
//
#include <hip/hip_runtime.h>
#include <hip/hip_bf16.h>
#include <math.h>

#define NN 16384
#define NE 262144
#define NB 64
#define FD 32
#define NT 8
#define NL 3
#define NH 128
#define EPSV 1e-5f

typedef unsigned short u16;
typedef unsigned int u32;
typedef long long i64;

static __device__ __forceinline__ float us2f(u16 u){
  union { u32 i; float f; } z; z.i = ((u32)u) << 16; return z.f;
}

__global__ void k_diag(float* out, float v){
  int i = threadIdx.x;
  if (i < 128) out[i] = v;
}

// ---------- weight dtype detect ----------
__global__ __launch_bounds__(256) void k_detect(const u16* __restrict__ ne, int* __restrict__ flags){
  __shared__ float red[256];
  const int tid = threadIdx.x;
  float m = 0.f;
  for (int i=tid; i<1024; i+=256) m = fmaxf(m, fabsf(us2f(ne[i])));
  red[tid]=m; __syncthreads();
  for (int off=128; off>0; off>>=1){ if (tid<off) red[tid]=fmaxf(red[tid],red[tid+off]); __syncthreads(); }
  if (tid==0) flags[0] = (red[0] > 100.f) ? 1 : 0;
}

// ---------- int width detect ----------
__global__ __launch_bounds__(256) void k_det_i64(const int* __restrict__ ei_raw, int* __restrict__ flags){
  __shared__ int red[256];
  const int tid = threadIdx.x;
  int i = blockIdx.x*256 + tid;
  int c = (i < NE && ei_raw[2*i+1] == 0) ? 1 : 0;
  red[tid]=c; __syncthreads();
  for (int off=128; off>0; off>>=1){ if (tid<off) red[tid]+=red[tid+off]; __syncthreads(); }
  if (tid==0) atomicAdd(&flags[4], red[0]);
}
__global__ void k_set_i64(int* __restrict__ flags){
  flags[2] = (flags[4] > NE/4) ? 1 : 0;
}

struct IJobs { const void* src[4]; int* dst[4]; int cnt[4]; };
__global__ __launch_bounds__(256) void k_cvt_int(IJobs jb, const int* __restrict__ flags, int total){
  int i = blockIdx.x*256 + threadIdx.x;
  if (i >= total) return;
  const int m = flags[2];
  int a = 0, off = i;
  while (off >= jb.cnt[a]){ off -= jb.cnt[a]; a++; }
  int v = m ? (int)((const i64*)jb.src[a])[off] : ((const int*)jb.src[a])[off];
  jb.dst[a][off] = v;
}

struct Jobs { const void* src[20]; float* dst[20]; int cnt[20]; };
__global__ __launch_bounds__(256) void k_cvt(Jobs jb, const int* __restrict__ flags, int total){
  int i = blockIdx.x*256 + threadIdx.x;
  if (i >= total) return;
  const int m = flags[0];
  int a = 0, off = i;
  while (off >= jb.cnt[a]){ off -= jb.cnt[a]; a++; }
  float v = m ? ((const float*)jb.src[a])[off]
              : us2f(((const u16*)jb.src[a])[off]);
  jb.dst[a][off] = v;
}

// ---------------- CSR build ----------------
__global__ void k_count(const int* __restrict__ dst, int* __restrict__ deg){
  int e = blockIdx.x*256 + threadIdx.x;
  if (e < NE) atomicAdd(&deg[dst[e]], 1);
}

__global__ __launch_bounds__(256) void k_scan(const int* __restrict__ deg, int* __restrict__ offs){
  __shared__ int part[257];
  const int tid = threadIdx.x;
  int s = 0;
  for (int i=0;i<64;i++) s += deg[tid*64+i];
  part[tid+1] = s;
  __syncthreads();
  if (tid==0){ part[0]=0; for (int i=1;i<=256;i++) part[i]+=part[i-1]; }
  __syncthreads();
  int run = part[tid];
  for (int i=0;i<64;i++){ offs[tid*64+i]=run; run+=deg[tid*64+i]; }
  if (tid==255) offs[NN]=run;
}

__global__ void k_fill(const int* __restrict__ src, const int* __restrict__ dst,
                       const int* __restrict__ ea_in, const int* __restrict__ offs,
                       int* __restrict__ cursor, int* __restrict__ esrc, int* __restrict__ eatt){
  int e = blockIdx.x*256 + threadIdx.x;
  if (e < NE){
    int d = dst[e];
    int pslot = atomicAdd(&cursor[d], 1);
    int idx = offs[d] + pslot;
    esrc[idx] = src[e];
    eatt[idx] = ea_in[e];
  }
}

// ---------------- avg log + scalers ----------------
__global__ __launch_bounds__(256) void k_logsumF(const int* __restrict__ deg, double* __restrict__ lsum){
  __shared__ double red[256];
  const int tid = threadIdx.x;
  double s = 0.0;
  for (int n=tid; n<NN; n+=256) s += log((double)deg[n] + 1.0);
  red[tid]=s; __syncthreads();
  for (int off=128; off>0; off>>=1){ if (tid<off) red[tid]+=red[tid+off]; __syncthreads(); }
  if (tid==0) *lsum = red[0] / (double)NN;
}

__global__ void k_scalersF(const int* __restrict__ deg, const double* __restrict__ lsum,
                           float* __restrict__ amp, float* __restrict__ attn, float* __restrict__ invc){
  int n = blockIdx.x*256 + threadIdx.x;
  if (n >= NN) return;
  float avg = (float)(*lsum);
  int d = deg[n]; int dc = d > 0 ? d : 1;
  float la = logf((float)dc + 1.0f);
  amp[n] = la/avg; attn[n] = avg/la; invc[n] = 1.0f/(float)dc;
}

// ---------------- embedding ----------------
__global__ void k_embed(const int* __restrict__ x, const float* __restrict__ emb,
                        float* __restrict__ h){
  int i = blockIdx.x*256 + threadIdx.x;
  if (i < NN*FD){
    int n = i>>5, f = i&31;
    h[i] = emb[x[n]*FD + f];
  }
}

// ---------------- edge-attr encode + etab ----------------
__global__ void k_eenc(const float* __restrict__ ee, const float* __restrict__ Wee,
                       const float* __restrict__ bee, float* __restrict__ eenc, int l){
  int i = blockIdx.x*256 + threadIdx.x;
  if (i >= 16*FD) return;
  int a = i>>5, f2 = i&31;
  float acc = bee[l*FD + f2];
  for (int c2=0; c2<16; c2++)
    acc = fmaf(ee[a*16+c2], Wee[(l*16+c2)*FD+f2], acc);
  eenc[i] = acc;
}

__global__ __launch_bounds__(256) void k_etab2(const float* __restrict__ eenc, const float* __restrict__ Wpre,
                      float* __restrict__ etab, int l){
  int i = blockIdx.x*256 + threadIdx.x;
  if (i >= 16*256) return;
  int a = i>>8, dd = i&255, t = dd>>5, f = dd&31;
  float acc = 0.f;
  for (int f2=0; f2<FD; f2++)
    acc = fmaf(eenc[a*FD+f2], Wpre[((l*NT+t)*96 + 64 + f2)*FD + f], acc);
  etab[i] = acc;
}

// ---------------- per-node pre: nbase = h@Wd + bpre, psrc = h@Ws ----------------
__global__ __launch_bounds__(256) void k_pre(const float* __restrict__ h,
                     const float* __restrict__ Wpre, const float* __restrict__ bpre,
                     float* __restrict__ nbase, float* __restrict__ psrc, int l){
  __shared__ float hl[64*FD];
  const int tid = threadIdx.x;
  const int t = tid>>5, f = tid&31;
  float wd[32], ws[32];
  #pragma unroll
  for (int c=0;c<FD;c++){
    wd[c] = Wpre[((l*NT+t)*96 + c)*FD + f];
    ws[c] = Wpre[((l*NT+t)*96 + 32 + c)*FD + f];
  }
  const float bb = bpre[(l*NT+t)*FD + f];
  const int n0 = blockIdx.x*64;
  for (int i=tid; i<64*FD; i+=256) hl[i] = h[n0*FD + i];
  __syncthreads();
  for (int nn=0; nn<64; nn++){
    float ad=bb, as=0.f;
    #pragma unroll
    for (int c=0;c<FD;c++){ float hv=hl[nn*FD+c]; ad=fmaf(hv,wd[c],ad); as=fmaf(hv,ws[c],as); }
    const int n = n0+nn;
    nbase[(size_t)n*256+tid]=ad; psrc[(size_t)n*256+tid]=as;
  }
}

// ---------------- fused wave-per-node aggregation + post-MLP + Wlin ----------------
__global__ __launch_bounds__(256) void k_agg(
    const float* __restrict__ nbase, const float* __restrict__ psrc,
    const float* __restrict__ etab,
    const int* __restrict__ esrc, const int* __restrict__ eatt, const int* __restrict__ offs,
    const float* __restrict__ h, const float* __restrict__ amp,
    const float* __restrict__ attn, const float* __restrict__ invc,
    const float* __restrict__ Wpost, const float* __restrict__ bpost,
    const float* __restrict__ Wlin, const float* __restrict__ blin,
    float* __restrict__ z, int l)
{
  __shared__ u16 wp[13312];
  __shared__ float wl[1024];
  __shared__ float bpo[32], bli[32];
  const int tid = threadIdx.x;
  const float* WpL = Wpost + (size_t)l*13312;
  for (int i=tid;i<13312;i+=256) wp[i] = (u16)(__float_as_uint(WpL[i])>>16);
  for (int i=tid;i<1024;i+=256) wl[i] = Wlin[l*1024+i];
  if (tid<32){ bpo[tid]=bpost[l*32+tid]; bli[tid]=blin[l*32+tid]; }
  __syncthreads();
  const int wid = tid>>6, lane = tid&63;
  const int t = lane>>3, q = lane&7;
  for (int sw=0; sw<4; sw++){
    const int n = blockIdx.x*16 + wid*4 + sw;
    const int o0 = offs[n], o1 = offs[n+1];
    float bs[4]; *(float4*)bs = *(const float4*)(nbase + (size_t)n*256 + lane*4);
    float sum[4]={0,0,0,0}, sq[4]={0,0,0,0}, mn[4], mx[4];
    #pragma unroll
    for (int k=0;k<4;k++){ mn[k]=__builtin_inff(); mx[k]=-__builtin_inff(); }
    for (int j=o0; j<o1; j++){
      const int s = esrc[j];
      const int a = eatt[j];
      float pv[4]; *(float4*)pv = *(const float4*)(psrc + (size_t)s*256 + lane*4);
      float ev[4]; *(float4*)ev = *(const float4*)(etab + a*256 + lane*4);
      #pragma unroll
      for (int k=0;k<4;k++){
        float v = bs[k] + pv[k] + ev[k];
        sum[k]+=v; sq[k]=fmaf(v,v,sq[k]); mn[k]=fminf(mn[k],v); mx[k]=fmaxf(mx[k],v);
      }
    }
    const int dg = o1-o0;
    const float ic = invc[n];
    float aggv[4][4];
    #pragma unroll
    for (int k=0;k<4;k++){
      float mean = sum[k]*ic;
      float ms = sq[k]*ic;
      float var = fmaxf(ms - mean*mean, 0.f);
      aggv[0][k]=mean;
      aggv[1][k]=(dg>0)?mn[k]:0.f;
      aggv[2][k]=(dg>0)?mx[k]:0.f;
      aggv[3][k]=sqrtf(var+EPSV);
    }
    const float av = amp[n], at_ = attn[n];
    float acc[4]={0,0,0,0};
    float hv[4]; *(float4*)hv = *(const float4*)(h + n*FD + q*4);
    #pragma unroll
    for (int k=0;k<4;k++){
      int c = q*4+k;
      #pragma unroll
      for (int j=0;j<4;j++)
        acc[j] = fmaf(hv[k], us2f(wp[(t*416+c)*4+j]), acc[j]);
    }
    #pragma unroll
    for (int g=0; g<4; g++){
      #pragma unroll
      for (int k=0;k<4;k++){
        float a_ = aggv[g][k];
        int rb = 32 + g*32 + q*4 + k;
        #pragma unroll
        for (int j=0;j<4;j++){
          float w = us2f(wp[(t*416+rb)*4+j])
                  + av*us2f(wp[(t*416+rb+128)*4+j])
                  + at_*us2f(wp[(t*416+rb+256)*4+j]);
          acc[j] = fmaf(a_, w, acc[j]);
        }
      }
    }
    #pragma unroll
    for (int j=0;j<4;j++){
      acc[j] += __shfl_xor(acc[j], 1);
      acc[j] += __shfl_xor(acc[j], 2);
      acc[j] += __shfl_xor(acc[j], 4);
      acc[j] += bpo[t*4+j];
    }
    float zv = 0.f;
    #pragma unroll
    for (int dp=0; dp<32; dp++){
      float v = __shfl(acc[dp&3], (dp>>2)*8);
      zv = fmaf(v, wl[dp*32 + (lane&31)], zv);
    }
    if (lane < 32) z[n*FD + lane] = zv + bli[lane];
  }
}

// ---------------- BN: two-pass f64 ----------------
__global__ __launch_bounds__(256) void k_sum1(const float* __restrict__ z, double* __restrict__ st){
  const int tid = threadIdx.x;
  const int f = tid&31, rg = tid>>5;
  double s = 0.0;
  for (int n = blockIdx.x*8 + rg; n < NN; n += 512) s += (double)z[n*FD+f];
  __shared__ double l1[256];
  l1[tid]=s; __syncthreads();
  if (rg<4) l1[tid]+=l1[tid+128]; __syncthreads();
  if (rg<2) l1[tid]+=l1[tid+64];  __syncthreads();
  if (rg<1) atomicAdd(&st[f], l1[tid]+l1[tid+32]);
}
__global__ __launch_bounds__(256) void k_sum2(const float* __restrict__ z, const double* __restrict__ st,
                                              double* __restrict__ st2){
  const int tid = threadIdx.x;
  const int f = tid&31, rg = tid>>5;
  const double mu = st[f] * (1.0/(double)NN);
  double s = 0.0;
  for (int n = blockIdx.x*8 + rg; n < NN; n += 512){
    double d = (double)z[n*FD+f] - mu; s += d*d;
  }
  __shared__ double l1[256];
  l1[tid]=s; __syncthreads();
  if (rg<4) l1[tid]+=l1[tid+128]; __syncthreads();
  if (rg<2) l1[tid]+=l1[tid+64];  __syncthreads();
  if (rg<1) atomicAdd(&st2[f], l1[tid]+l1[tid+32]);
}
__global__ void k_bnF(const float* __restrict__ z, const double* __restrict__ st,
                      const double* __restrict__ st2,
                      const float* __restrict__ bng, const float* __restrict__ bnb,
                      float* __restrict__ h, int l){
  int i = blockIdx.x*256 + threadIdx.x;
  if (i >= NN*FD) return;
  int f = i&31;
  float mu  = (float)(st[f]  * (1.0/(double)NN));
  float var = (float)(st2[f] * (1.0/(double)NN));
  float sc = bng[l*FD+f]*rsqrtf(var+EPSV);
  float v = (z[i]-mu)*sc + bnb[l*FD+f];
  h[i] = fmaxf(v, 0.f);
}

// ---------------- pooling ----------------
__global__ __launch_bounds__(256) void k_poolF(const float* __restrict__ h, const int* __restrict__ batch,
                                               float* __restrict__ g){
  __shared__ float acc[8][FD];
  const int b = blockIdx.x;
  const int tid = threadIdx.x;
  const int f = tid&31, rg = tid>>5;
  float s = 0.f;
  for (int n=rg; n<NN; n+=8)
    if (batch[n] == b) s += h[n*FD+f];
  acc[rg][f] = s; __syncthreads();
  if (rg == 0){
    float t = 0.f;
    for (int r=0;r<8;r++) t += acc[r][f];
    g[b*FD+f] = t;
  }
}

// ---------------- head: 512 threads, LDS ping-pong, no spills ----------------
__global__ __launch_bounds__(512) void k_head2(
    const float* __restrict__ gpool,
    const float* __restrict__ Wm0, const float* __restrict__ bm0,
    const float* __restrict__ Wmh, const float* __restrict__ bmh,
    const float* __restrict__ bnmg, const float* __restrict__ bnmb,
    const float* __restrict__ Wf, const float* __restrict__ bfv,
    float* __restrict__ out)
{
  __shared__ float A[NB*NH];
  __shared__ float Bb[NB*NH];
  const int tid = threadIdx.x;
  // stage gpool into Bb[0:2048]
  for (int i=tid;i<NB*FD;i+=512) Bb[i]=gpool[i];
  __syncthreads();
  // L0: A[b*128+hh]
  for (int k=0;k<16;k++){
    int o = tid + k*512; int b=o>>7, hh=o&127;
    float acc = bm0[hh];
    for (int c=0;c<FD;c++) acc = fmaf(Bb[b*FD+c], Wm0[c*NH+hh], acc);
    A[o]=acc;
  }
  __syncthreads();
  if (tid<NH){
    double s=0.0; for (int b=0;b<NB;b++) s += (double)A[b*NH+tid];
    double mu = s/(double)NB;
    double v=0.0; for (int b=0;b<NB;b++){ double d=(double)A[b*NH+tid]-mu; v+=d*d; }
    v /= (double)NB;
    float sc = bnmg[tid]*rsqrtf((float)v+EPSV);
    float sh = bnmb[tid]-(float)mu*sc;
    for (int b=0;b<NB;b++) A[b*NH+tid] = fmaxf(A[b*NH+tid]*sc+sh, 0.f);
  }
  __syncthreads();
  for (int i=0;i<2;i++){
    float* sp = (i==0) ? A : Bb;
    float* dp = (i==0) ? Bb : A;
    for (int k=0;k<16;k++){
      int o = tid + k*512; int b=o>>7, hh=o&127;
      float acc = bmh[i*NH+hh];
      for (int c=0;c<NH;c++) acc = fmaf(sp[b*NH+c], Wmh[(i*NH+c)*NH+hh], acc);
      dp[o]=acc;
    }
    __syncthreads();
    if (tid<NH){
      double s=0.0; for (int b=0;b<NB;b++) s += (double)dp[b*NH+tid];
      double mu = s/(double)NB;
      double v=0.0; for (int b=0;b<NB;b++){ double d=(double)dp[b*NH+tid]-mu; v+=d*d; }
      v /= (double)NB;
      float sc = bnmg[(i+1)*NH+tid]*rsqrtf((float)v+EPSV);
      float sh = bnmb[(i+1)*NH+tid]-(float)mu*sc;
      for (int b=0;b<NB;b++) dp[b*NH+tid] = fmaxf(dp[b*NH+tid]*sc+sh, 0.f);
    }
    __syncthreads();
  }
  // final from A (i=1 wrote A)
  if (tid < NB){
    float acc = bfv[0];
    for (int c=0;c<NH;c++) acc = fmaf(A[tid*NH+c], Wf[c], acc);
    out[NB+tid] = acc;
    out[tid]    = 1.f/(1.f+expf(-acc));
  }
}

extern "C" void kernel_launch(void* const* d_in, const int* in_sizes, int n_in,
                              void* d_out, int out_size, void* d_ws, size_t ws_size,
                              hipStream_t stream)
{
  float* out = (float*)d_out;

  static const int EXP_SZ[24] = {16384, 524288, 262144, 16384, 1024, 256, 1536, 96,
                                 73728, 768, 39936, 96, 3072, 96, 96, 96,
                                 4096, 128, 32768, 256, 384, 384, 128, 1};
  int bad = -1;
  if (n_in != 24) bad = 24;
  else for (int i=0;i<24;i++){ if (in_sizes[i] != EXP_SZ[i]){ bad = i; break; } }
  if (bad >= 0){
    k_diag<<<1, 128, 0, stream>>>(out, 512.0f + 8.0f*(float)bad);
    return;
  }

  char* p = (char*)d_ws;
  auto carve = [&](size_t bytes)->char*{ char* r = p; p += (bytes + 255) & ~(size_t)255; return r; };
  int*    flags = (int*)carve(64);
  int*    deg   = (int*)carve((size_t)NN*4);
  int*    cursor= (int*)carve((size_t)NN*4);
  int*    offs  = (int*)carve((size_t)(NN+1)*4);
  int*    esrc  = (int*)carve((size_t)NE*4);
  int*    eatt  = (int*)carve((size_t)NE*4);
  float*  h     = (float*)carve((size_t)NN*FD*4);
  float*  z     = (float*)carve((size_t)NN*FD*4);
  float*  nbase = (float*)carve((size_t)NN*256*4);
  float*  psrc  = (float*)carve((size_t)NN*256*4);
  float*  etab  = (float*)carve(4096*4);
  float*  eenc  = (float*)carve(16*FD*4);
  float*  amp   = (float*)carve((size_t)NN*4);
  float*  attn  = (float*)carve((size_t)NN*4);
  float*  invc  = (float*)carve((size_t)NN*4);
  double* lsum  = (double*)carve(8);
  double* st1   = (double*)carve(32*8);
  double* st2   = (double*)carve(32*8);
  float*  gp    = (float*)carve((size_t)NB*FD*4);
  int*    cx    = (int*)carve((size_t)NN*4);
  int*    cei   = (int*)carve((size_t)2*NE*4);
  int*    cea   = (int*)carve((size_t)NE*4);
  int*    cbatch= (int*)carve((size_t)NN*4);

  Jobs jb;
  float* wptr[24];
  int total = 0;
  {
    float* cur = (float*)carve(700*1024);
    for (int i=4; i<24; i++){
      jb.src[i-4] = d_in[i];
      jb.dst[i-4] = cur;
      jb.cnt[i-4] = in_sizes[i];
      wptr[i] = cur;
      cur += in_sizes[i];
      total += in_sizes[i];
    }
  }
  const size_t need = (size_t)(p - (char*)d_ws);
  if (ws_size < need){
    k_diag<<<1, 128, 0, stream>>>(out, -2000.0f - (float)(ws_size >> 20));
    return;
  }

  IJobs ij;
  ij.src[0]=d_in[0]; ij.dst[0]=cx;     ij.cnt[0]=NN;
  ij.src[1]=d_in[1]; ij.dst[1]=cei;    ij.cnt[1]=2*NE;
  ij.src[2]=d_in[2]; ij.dst[2]=cea;    ij.cnt[2]=NE;
  ij.src[3]=d_in[3]; ij.dst[3]=cbatch; ij.cnt[3]=NN;
  const int itotal = NN + 2*NE + NE + NN;

  const float* ne_f   = wptr[4];
  const float* ee_f   = wptr[5];
  const float* Wee_f  = wptr[6];
  const float* bee_f  = wptr[7];
  const float* Wpre_f = wptr[8];
  const float* bpre_f = wptr[9];
  const float* Wpost_f= wptr[10];
  const float* bpost_f= wptr[11];
  const float* Wlin_f = wptr[12];
  const float* blin_f = wptr[13];
  const float* bng_f  = wptr[14];
  const float* bnb_f  = wptr[15];
  const float* Wm0_f  = wptr[16];
  const float* bm0_f  = wptr[17];
  const float* Wmh_f  = wptr[18];
  const float* bmh_f  = wptr[19];
  const float* bnmg_f = wptr[20];
  const float* bnmb_f = wptr[21];
  const float* Wf_f   = wptr[22];
  const float* bf_f   = wptr[23];

  hipMemsetAsync(flags, 0, 64, stream);
  hipMemsetAsync(deg, 0, (size_t)NN*4, stream);
  hipMemsetAsync(cursor, 0, (size_t)NN*4, stream);

  k_detect<<<1, 256, 0, stream>>>((const u16*)d_in[4], flags);
  k_det_i64<<<NE/256, 256, 0, stream>>>((const int*)d_in[1], flags);
  k_set_i64<<<1, 1, 0, stream>>>(flags);
  k_cvt_int<<<(itotal+255)/256, 256, 0, stream>>>(ij, flags, itotal);
  k_cvt<<<(total+255)/256, 256, 0, stream>>>(jb, flags, total);

  k_count<<<NE/256, 256, 0, stream>>>(cei+NE, deg);
  k_scan<<<1, 256, 0, stream>>>(deg, offs);
  k_fill<<<NE/256, 256, 0, stream>>>(cei, cei+NE, cea, offs, cursor, esrc, eatt);
  k_logsumF<<<1, 256, 0, stream>>>(deg, lsum);
  k_scalersF<<<NN/256, 256, 0, stream>>>(deg, lsum, amp, attn, invc);
  k_embed<<<NN*FD/256, 256, 0, stream>>>(cx, ne_f, h);

  for (int l=0; l<NL; l++){
    k_eenc<<<2, 256, 0, stream>>>(ee_f, Wee_f, bee_f, eenc, l);
    k_etab2<<<16, 256, 0, stream>>>(eenc, Wpre_f, etab, l);
    k_pre<<<NN/64, 256, 0, stream>>>(h, Wpre_f, bpre_f, nbase, psrc, l);
    k_agg<<<NN/16, 256, 0, stream>>>(nbase, psrc, etab, esrc, eatt, offs, h, amp, attn, invc,
                                     Wpost_f, bpost_f, Wlin_f, blin_f, z, l);
    hipMemsetAsync(st1, 0, 32*8, stream);
    hipMemsetAsync(st2, 0, 32*8, stream);
    k_sum1<<<64, 256, 0, stream>>>(z, st1);
    k_sum2<<<64, 256, 0, stream>>>(z, st1, st2);
    k_bnF<<<NN*FD/256, 256, 0, stream>>>(z, st1, st2, bng_f, bnb_f, h, l);
  }

  k_poolF<<<NB, 256, 0, stream>>>(h, cbatch, gp);
  k_head2<<<1, 512, 0, stream>>>(gp, Wm0_f, bm0_f, Wmh_f, bmh_f, bnmg_f, bnmb_f, Wf_f, bf_f, out);
}

// Round 10
// 511.633 us; speedup vs baseline: 13.1823x; 2.3405x over previous
//
#include <hip/hip_runtime.h>
#include <hip/hip_bf16.h>
#include <math.h>

#define NN 16384
#define NE 262144
#define NB 64
#define FD 32
#define NT 8
#define NL 3
#define NH 128
#define EPSV 1e-5f

typedef unsigned short u16;
typedef unsigned int u32;
typedef long long i64;

static __device__ __forceinline__ float us2f(u16 u){
  union { u32 i; float f; } z; z.i = ((u32)u) << 16; return z.f;
}

__global__ void k_diag(float* out, float v){
  int i = threadIdx.x;
  if (i < 128) out[i] = v;
}

// ---------- weight dtype detect ----------
__global__ __launch_bounds__(256) void k_detect(const u16* __restrict__ ne, int* __restrict__ flags){
  __shared__ float red[256];
  const int tid = threadIdx.x;
  float m = 0.f;
  for (int i=tid; i<1024; i+=256) m = fmaxf(m, fabsf(us2f(ne[i])));
  red[tid]=m; __syncthreads();
  for (int off=128; off>0; off>>=1){ if (tid<off) red[tid]=fmaxf(red[tid],red[tid+off]); __syncthreads(); }
  if (tid==0) flags[0] = (red[0] > 100.f) ? 1 : 0;
}

// ---------- int width detect ----------
__global__ __launch_bounds__(256) void k_det_i64(const int* __restrict__ ei_raw, int* __restrict__ flags){
  __shared__ int red[256];
  const int tid = threadIdx.x;
  int i = blockIdx.x*256 + tid;
  int c = (i < NE && ei_raw[2*i+1] == 0) ? 1 : 0;
  red[tid]=c; __syncthreads();
  for (int off=128; off>0; off>>=1){ if (tid<off) red[tid]+=red[tid+off]; __syncthreads(); }
  if (tid==0) atomicAdd(&flags[4], red[0]);
}
__global__ void k_set_i64(int* __restrict__ flags){
  flags[2] = (flags[4] > NE/4) ? 1 : 0;
}

struct IJobs { const void* src[4]; int* dst[4]; int cnt[4]; };
__global__ __launch_bounds__(256) void k_cvt_int(IJobs jb, const int* __restrict__ flags, int total){
  int i = blockIdx.x*256 + threadIdx.x;
  if (i >= total) return;
  const int m = flags[2];
  int a = 0, off = i;
  while (off >= jb.cnt[a]){ off -= jb.cnt[a]; a++; }
  int v = m ? (int)((const i64*)jb.src[a])[off] : ((const int*)jb.src[a])[off];
  jb.dst[a][off] = v;
}

struct Jobs { const void* src[20]; float* dst[20]; int cnt[20]; };
__global__ __launch_bounds__(256) void k_cvt(Jobs jb, const int* __restrict__ flags, int total){
  int i = blockIdx.x*256 + threadIdx.x;
  if (i >= total) return;
  const int m = flags[0];
  int a = 0, off = i;
  while (off >= jb.cnt[a]){ off -= jb.cnt[a]; a++; }
  float v = m ? ((const float*)jb.src[a])[off]
              : us2f(((const u16*)jb.src[a])[off]);
  jb.dst[a][off] = v;
}

// ---------------- CSR build ----------------
__global__ void k_count(const int* __restrict__ dst, int* __restrict__ deg){
  int e = blockIdx.x*256 + threadIdx.x;
  if (e < NE) atomicAdd(&deg[dst[e]], 1);
}

__global__ __launch_bounds__(256) void k_scan(const int* __restrict__ deg, int* __restrict__ offs){
  __shared__ int part[257];
  const int tid = threadIdx.x;
  int s = 0;
  for (int i=0;i<64;i++) s += deg[tid*64+i];
  part[tid+1] = s;
  __syncthreads();
  if (tid==0){ part[0]=0; for (int i=1;i<=256;i++) part[i]+=part[i-1]; }
  __syncthreads();
  int run = part[tid];
  for (int i=0;i<64;i++){ offs[tid*64+i]=run; run+=deg[tid*64+i]; }
  if (tid==255) offs[NN]=run;
}

__global__ void k_fill(const int* __restrict__ src, const int* __restrict__ dst,
                       const int* __restrict__ ea_in, const int* __restrict__ offs,
                       int* __restrict__ cursor, int* __restrict__ esrc, int* __restrict__ eatt){
  int e = blockIdx.x*256 + threadIdx.x;
  if (e < NE){
    int d = dst[e];
    int pslot = atomicAdd(&cursor[d], 1);
    int idx = offs[d] + pslot;
    esrc[idx] = src[e];
    eatt[idx] = ea_in[e];
  }
}

// ---------------- avg log + scalers ----------------
__global__ __launch_bounds__(256) void k_logsumF(const int* __restrict__ deg, double* __restrict__ lsum){
  __shared__ double red[256];
  const int tid = threadIdx.x;
  double s = 0.0;
  for (int n=tid; n<NN; n+=256) s += log((double)deg[n] + 1.0);
  red[tid]=s; __syncthreads();
  for (int off=128; off>0; off>>=1){ if (tid<off) red[tid]+=red[tid+off]; __syncthreads(); }
  if (tid==0) *lsum = red[0] / (double)NN;
}

__global__ void k_scalersF(const int* __restrict__ deg, const double* __restrict__ lsum,
                           float* __restrict__ amp, float* __restrict__ attn, float* __restrict__ invc){
  int n = blockIdx.x*256 + threadIdx.x;
  if (n >= NN) return;
  float avg = (float)(*lsum);
  int d = deg[n]; int dc = d > 0 ? d : 1;
  float la = logf((float)dc + 1.0f);
  amp[n] = la/avg; attn[n] = avg/la; invc[n] = 1.0f/(float)dc;
}

// ---------------- embedding ----------------
__global__ void k_embed(const int* __restrict__ x, const float* __restrict__ emb,
                        float* __restrict__ h){
  int i = blockIdx.x*256 + threadIdx.x;
  if (i < NN*FD){
    int n = i>>5, f = i&31;
    h[i] = emb[x[n]*FD + f];
  }
}

// ---------------- edge-attr encode + etab ----------------
__global__ void k_eenc(const float* __restrict__ ee, const float* __restrict__ Wee,
                       const float* __restrict__ bee, float* __restrict__ eenc, int l){
  int i = blockIdx.x*256 + threadIdx.x;
  if (i >= 16*FD) return;
  int a = i>>5, f2 = i&31;
  float acc = bee[l*FD + f2];
  for (int c2=0; c2<16; c2++)
    acc = fmaf(ee[a*16+c2], Wee[(l*16+c2)*FD+f2], acc);
  eenc[i] = acc;
}

__global__ __launch_bounds__(256) void k_etab2(const float* __restrict__ eenc, const float* __restrict__ Wpre,
                      float* __restrict__ etab, int l){
  int i = blockIdx.x*256 + threadIdx.x;
  if (i >= 16*256) return;
  int a = i>>8, dd = i&255, t = dd>>5, f = dd&31;
  float acc = 0.f;
  for (int f2=0; f2<FD; f2++)
    acc = fmaf(eenc[a*FD+f2], Wpre[((l*NT+t)*96 + 64 + f2)*FD + f], acc);
  etab[i] = acc;
}

// ---------------- per-node pre: nbase = h@Wd + bpre, psrc = h@Ws ----------------
__global__ __launch_bounds__(256) void k_pre(const float* __restrict__ h,
                     const float* __restrict__ Wpre, const float* __restrict__ bpre,
                     float* __restrict__ nbase, float* __restrict__ psrc, int l){
  __shared__ float hl[64*FD];
  const int tid = threadIdx.x;
  const int t = tid>>5, f = tid&31;
  float wd[32], ws[32];
  #pragma unroll
  for (int c=0;c<FD;c++){
    wd[c] = Wpre[((l*NT+t)*96 + c)*FD + f];
    ws[c] = Wpre[((l*NT+t)*96 + 32 + c)*FD + f];
  }
  const float bb = bpre[(l*NT+t)*FD + f];
  const int n0 = blockIdx.x*64;
  for (int i=tid; i<64*FD; i+=256) hl[i] = h[n0*FD + i];
  __syncthreads();
  for (int nn=0; nn<64; nn++){
    float ad=bb, as=0.f;
    #pragma unroll
    for (int c=0;c<FD;c++){ float hv=hl[nn*FD+c]; ad=fmaf(hv,wd[c],ad); as=fmaf(hv,ws[c],as); }
    const int n = n0+nn;
    nbase[(size_t)n*256+tid]=ad; psrc[(size_t)n*256+tid]=as;
  }
}

// ---------------- fused aggregation + post-MLP + Wlin: 16 waves/block, 1 node/wave ----------------
__global__ __launch_bounds__(1024) void k_agg(
    const float* __restrict__ nbase, const float* __restrict__ psrc,
    const float* __restrict__ etab,
    const int* __restrict__ esrc, const int* __restrict__ eatt, const int* __restrict__ offs,
    const float* __restrict__ h, const float* __restrict__ amp,
    const float* __restrict__ attn, const float* __restrict__ invc,
    const float* __restrict__ Wpost, const float* __restrict__ bpost,
    const float* __restrict__ Wlin, const float* __restrict__ blin,
    float* __restrict__ z, int l)
{
  __shared__ u16 wp[13312];
  __shared__ float wl[1024];
  __shared__ float bpo[32], bli[32];
  const int tid = threadIdx.x;
  const float* WpL = Wpost + (size_t)l*13312;
  for (int i=tid;i<13312;i+=1024) wp[i] = (u16)(__float_as_uint(WpL[i])>>16);
  if (tid < 1024) wl[tid] = Wlin[l*1024+tid];
  if (tid<32){ bpo[tid]=bpost[l*32+tid]; bli[tid]=blin[l*32+tid]; }
  __syncthreads();
  const int wid = tid>>6, lane = tid&63;
  const int t = lane>>3, q = lane&7;
  const int n = blockIdx.x*16 + wid;
  const int o0 = offs[n], o1 = offs[n+1];
  float bs[4]; *(float4*)bs = *(const float4*)(nbase + (size_t)n*256 + lane*4);
  float sum[4]={0,0,0,0}, sq[4]={0,0,0,0}, mn[4], mx[4];
  #pragma unroll
  for (int k=0;k<4;k++){ mn[k]=__builtin_inff(); mx[k]=-__builtin_inff(); }
  int j = o0;
  for (; j+3 < o1; j+=4){
    const int s0=esrc[j],   s1=esrc[j+1], s2=esrc[j+2], s3=esrc[j+3];
    const int a0=eatt[j],   a1=eatt[j+1], a2=eatt[j+2], a3=eatt[j+3];
    float4 p0 = *(const float4*)(psrc + (size_t)s0*256 + lane*4);
    float4 p1 = *(const float4*)(psrc + (size_t)s1*256 + lane*4);
    float4 p2 = *(const float4*)(psrc + (size_t)s2*256 + lane*4);
    float4 p3 = *(const float4*)(psrc + (size_t)s3*256 + lane*4);
    float4 e0 = *(const float4*)(etab + a0*256 + lane*4);
    float4 e1 = *(const float4*)(etab + a1*256 + lane*4);
    float4 e2 = *(const float4*)(etab + a2*256 + lane*4);
    float4 e3 = *(const float4*)(etab + a3*256 + lane*4);
    const float* pp0=(const float*)&p0; const float* ee0=(const float*)&e0;
    const float* pp1=(const float*)&p1; const float* ee1=(const float*)&e1;
    const float* pp2=(const float*)&p2; const float* ee2=(const float*)&e2;
    const float* pp3=(const float*)&p3; const float* ee3=(const float*)&e3;
    #pragma unroll
    for (int k=0;k<4;k++){
      float v0 = bs[k] + pp0[k] + ee0[k];
      float v1 = bs[k] + pp1[k] + ee1[k];
      float v2 = bs[k] + pp2[k] + ee2[k];
      float v3 = bs[k] + pp3[k] + ee3[k];
      sum[k] += (v0+v1)+(v2+v3);
      sq[k] = fmaf(v0,v0,sq[k]); sq[k] = fmaf(v1,v1,sq[k]);
      sq[k] = fmaf(v2,v2,sq[k]); sq[k] = fmaf(v3,v3,sq[k]);
      mn[k] = fminf(mn[k], fminf(fminf(v0,v1), fminf(v2,v3)));
      mx[k] = fmaxf(mx[k], fmaxf(fmaxf(v0,v1), fmaxf(v2,v3)));
    }
  }
  for (; j < o1; j++){
    const int s = esrc[j];
    const int a = eatt[j];
    float4 pv4 = *(const float4*)(psrc + (size_t)s*256 + lane*4);
    float4 ev4 = *(const float4*)(etab + a*256 + lane*4);
    const float* pv=(const float*)&pv4; const float* ev=(const float*)&ev4;
    #pragma unroll
    for (int k=0;k<4;k++){
      float v = bs[k] + pv[k] + ev[k];
      sum[k]+=v; sq[k]=fmaf(v,v,sq[k]); mn[k]=fminf(mn[k],v); mx[k]=fmaxf(mx[k],v);
    }
  }
  const int dg = o1-o0;
  const float ic = invc[n];
  float aggv[4][4];
  #pragma unroll
  for (int k=0;k<4;k++){
    float mean = sum[k]*ic;
    float ms = sq[k]*ic;
    float var = fmaxf(ms - mean*mean, 0.f);
    aggv[0][k]=mean;
    aggv[1][k]=(dg>0)?mn[k]:0.f;
    aggv[2][k]=(dg>0)?mx[k]:0.f;
    aggv[3][k]=sqrtf(var+EPSV);
  }
  const float av = amp[n], at_ = attn[n];
  float acc[4]={0,0,0,0};
  float hv[4]; *(float4*)hv = *(const float4*)(h + n*FD + q*4);
  #pragma unroll
  for (int k=0;k<4;k++){
    int c = q*4+k;
    #pragma unroll
    for (int jj=0;jj<4;jj++)
      acc[jj] = fmaf(hv[k], us2f(wp[(t*416+c)*4+jj]), acc[jj]);
  }
  #pragma unroll
  for (int g=0; g<4; g++){
    #pragma unroll
    for (int k=0;k<4;k++){
      float a_ = aggv[g][k];
      int rb = 32 + g*32 + q*4 + k;
      #pragma unroll
      for (int jj=0;jj<4;jj++){
        float w = us2f(wp[(t*416+rb)*4+jj])
                + av*us2f(wp[(t*416+rb+128)*4+jj])
                + at_*us2f(wp[(t*416+rb+256)*4+jj]);
        acc[jj] = fmaf(a_, w, acc[jj]);
      }
    }
  }
  #pragma unroll
  for (int jj=0;jj<4;jj++){
    acc[jj] += __shfl_xor(acc[jj], 1);
    acc[jj] += __shfl_xor(acc[jj], 2);
    acc[jj] += __shfl_xor(acc[jj], 4);
    acc[jj] += bpo[t*4+jj];
  }
  float zv = 0.f;
  #pragma unroll
  for (int dp=0; dp<32; dp++){
    float v = __shfl(acc[dp&3], (dp>>2)*8);
    zv = fmaf(v, wl[dp*32 + (lane&31)], zv);
  }
  if (lane < 32) z[n*FD + lane] = zv + bli[lane];
}

// ---------------- BN: single-pass f64 sum+sumsq ----------------
__global__ __launch_bounds__(256) void k_stats2(const float* __restrict__ z, double* __restrict__ st){
  const int tid = threadIdx.x;
  const int f = tid&31, rg = tid>>5;
  double s1=0.0, s2=0.0;
  for (int n = blockIdx.x*8 + rg; n < NN; n += 512){
    double v = (double)z[n*FD+f]; s1 += v; s2 += v*v;
  }
  __shared__ double l1[256], l2[256];
  l1[tid]=s1; l2[tid]=s2; __syncthreads();
  if (rg<4){ l1[tid]+=l1[tid+128]; l2[tid]+=l2[tid+128]; } __syncthreads();
  if (rg<2){ l1[tid]+=l1[tid+64];  l2[tid]+=l2[tid+64];  } __syncthreads();
  if (rg<1){
    atomicAdd(&st[f],    l1[tid]+l1[tid+32]);
    atomicAdd(&st[32+f], l2[tid]+l2[tid+32]);
  }
}
__global__ void k_bnF(const float* __restrict__ z, const double* __restrict__ st,
                      const float* __restrict__ bng, const float* __restrict__ bnb,
                      float* __restrict__ h, int l){
  int i = blockIdx.x*256 + threadIdx.x;
  if (i >= NN*FD) return;
  int f = i&31;
  double mu = st[f] * (1.0/(double)NN);
  double var = st[32+f] * (1.0/(double)NN) - mu*mu;
  float varf = fmaxf((float)var, 0.f);
  float sc = bng[l*FD+f]*rsqrtf(varf+EPSV);
  float v = (z[i]-(float)mu)*sc + bnb[l*FD+f];
  h[i] = fmaxf(v, 0.f);
}

// ---------------- pooling: segmented (batch sorted) ----------------
__global__ __launch_bounds__(256) void k_bounds(const int* __restrict__ batch, int* __restrict__ bstart){
  int n = blockIdx.x*256 + threadIdx.x;
  if (n >= NN) return;
  int b = batch[n];
  int prev = (n==0) ? -1 : batch[n-1];
  for (int v=prev+1; v<=b; v++) bstart[v]=n;
  if (n==NN-1) for (int v=b+1; v<=NB; v++) bstart[v]=NN;
}
__global__ __launch_bounds__(256) void k_pool2(const float* __restrict__ h, const int* __restrict__ bstart,
                                               float* __restrict__ g){
  __shared__ float acc[8][FD];
  const int b = blockIdx.x;
  const int tid = threadIdx.x;
  const int f = tid&31, rg = tid>>5;
  const int lo = bstart[b], hi = bstart[b+1];
  float s = 0.f;
  for (int n=lo+rg; n<hi; n+=8) s += h[n*FD+f];
  acc[rg][f] = s; __syncthreads();
  if (rg == 0){
    float t = 0.f;
    for (int r=0;r<8;r++) t += acc[r][f];
    g[b*FD+f] = t;
  }
}

// ---------------- head: 512 threads, LDS ping-pong ----------------
__global__ __launch_bounds__(512) void k_head2(
    const float* __restrict__ gpool,
    const float* __restrict__ Wm0, const float* __restrict__ bm0,
    const float* __restrict__ Wmh, const float* __restrict__ bmh,
    const float* __restrict__ bnmg, const float* __restrict__ bnmb,
    const float* __restrict__ Wf, const float* __restrict__ bfv,
    float* __restrict__ out)
{
  __shared__ float A[NB*NH];
  __shared__ float Bb[NB*NH];
  const int tid = threadIdx.x;
  for (int i=tid;i<NB*FD;i+=512) Bb[i]=gpool[i];
  __syncthreads();
  for (int k=0;k<16;k++){
    int o = tid + k*512; int b=o>>7, hh=o&127;
    float acc = bm0[hh];
    for (int c=0;c<FD;c++) acc = fmaf(Bb[b*FD+c], Wm0[c*NH+hh], acc);
    A[o]=acc;
  }
  __syncthreads();
  if (tid<NH){
    double s=0.0; for (int b=0;b<NB;b++) s += (double)A[b*NH+tid];
    double mu = s/(double)NB;
    double v=0.0; for (int b=0;b<NB;b++){ double d=(double)A[b*NH+tid]-mu; v+=d*d; }
    v /= (double)NB;
    float sc = bnmg[tid]*rsqrtf((float)v+EPSV);
    float sh = bnmb[tid]-(float)mu*sc;
    for (int b=0;b<NB;b++) A[b*NH+tid] = fmaxf(A[b*NH+tid]*sc+sh, 0.f);
  }
  __syncthreads();
  for (int i=0;i<2;i++){
    float* sp = (i==0) ? A : Bb;
    float* dp = (i==0) ? Bb : A;
    for (int k=0;k<16;k++){
      int o = tid + k*512; int b=o>>7, hh=o&127;
      float acc = bmh[i*NH+hh];
      for (int c=0;c<NH;c++) acc = fmaf(sp[b*NH+c], Wmh[(i*NH+c)*NH+hh], acc);
      dp[o]=acc;
    }
    __syncthreads();
    if (tid<NH){
      double s=0.0; for (int b=0;b<NB;b++) s += (double)dp[b*NH+tid];
      double mu = s/(double)NB;
      double v=0.0; for (int b=0;b<NB;b++){ double d=(double)dp[b*NH+tid]-mu; v+=d*d; }
      v /= (double)NB;
      float sc = bnmg[(i+1)*NH+tid]*rsqrtf((float)v+EPSV);
      float sh = bnmb[(i+1)*NH+tid]-(float)mu*sc;
      for (int b=0;b<NB;b++) dp[b*NH+tid] = fmaxf(dp[b*NH+tid]*sc+sh, 0.f);
    }
    __syncthreads();
  }
  if (tid < NB){
    float acc = bfv[0];
    for (int c=0;c<NH;c++) acc = fmaf(A[tid*NH+c], Wf[c], acc);
    out[NB+tid] = acc;
    out[tid]    = 1.f/(1.f+expf(-acc));
  }
}

extern "C" void kernel_launch(void* const* d_in, const int* in_sizes, int n_in,
                              void* d_out, int out_size, void* d_ws, size_t ws_size,
                              hipStream_t stream)
{
  float* out = (float*)d_out;

  static const int EXP_SZ[24] = {16384, 524288, 262144, 16384, 1024, 256, 1536, 96,
                                 73728, 768, 39936, 96, 3072, 96, 96, 96,
                                 4096, 128, 32768, 256, 384, 384, 128, 1};
  int bad = -1;
  if (n_in != 24) bad = 24;
  else for (int i=0;i<24;i++){ if (in_sizes[i] != EXP_SZ[i]){ bad = i; break; } }
  if (bad >= 0){
    k_diag<<<1, 128, 0, stream>>>(out, 512.0f + 8.0f*(float)bad);
    return;
  }

  char* p = (char*)d_ws;
  auto carve = [&](size_t bytes)->char*{ char* r = p; p += (bytes + 255) & ~(size_t)255; return r; };
  int*    flags = (int*)carve(64);
  int*    deg   = (int*)carve((size_t)NN*4);
  int*    cursor= (int*)carve((size_t)NN*4);
  int*    offs  = (int*)carve((size_t)(NN+1)*4);
  int*    esrc  = (int*)carve((size_t)NE*4);
  int*    eatt  = (int*)carve((size_t)NE*4);
  int*    bstart= (int*)carve((size_t)(NB+1)*4);
  float*  h     = (float*)carve((size_t)NN*FD*4);
  float*  z     = (float*)carve((size_t)NN*FD*4);
  float*  nbase = (float*)carve((size_t)NN*256*4);
  float*  psrc  = (float*)carve((size_t)NN*256*4);
  float*  etab  = (float*)carve(4096*4);
  float*  eenc  = (float*)carve(16*FD*4);
  float*  amp   = (float*)carve((size_t)NN*4);
  float*  attn  = (float*)carve((size_t)NN*4);
  float*  invc  = (float*)carve((size_t)NN*4);
  double* lsum  = (double*)carve(8);
  double* st1   = (double*)carve(64*8);
  float*  gp    = (float*)carve((size_t)NB*FD*4);
  int*    cx    = (int*)carve((size_t)NN*4);
  int*    cei   = (int*)carve((size_t)2*NE*4);
  int*    cea   = (int*)carve((size_t)NE*4);
  int*    cbatch= (int*)carve((size_t)NN*4);

  Jobs jb;
  float* wptr[24];
  int total = 0;
  {
    float* cur = (float*)carve(700*1024);
    for (int i=4; i<24; i++){
      jb.src[i-4] = d_in[i];
      jb.dst[i-4] = cur;
      jb.cnt[i-4] = in_sizes[i];
      wptr[i] = cur;
      cur += in_sizes[i];
      total += in_sizes[i];
    }
  }
  const size_t need = (size_t)(p - (char*)d_ws);
  if (ws_size < need){
    k_diag<<<1, 128, 0, stream>>>(out, -2000.0f - (float)(ws_size >> 20));
    return;
  }

  IJobs ij;
  ij.src[0]=d_in[0]; ij.dst[0]=cx;     ij.cnt[0]=NN;
  ij.src[1]=d_in[1]; ij.dst[1]=cei;    ij.cnt[1]=2*NE;
  ij.src[2]=d_in[2]; ij.dst[2]=cea;    ij.cnt[2]=NE;
  ij.src[3]=d_in[3]; ij.dst[3]=cbatch; ij.cnt[3]=NN;
  const int itotal = NN + 2*NE + NE + NN;

  const float* ne_f   = wptr[4];
  const float* ee_f   = wptr[5];
  const float* Wee_f  = wptr[6];
  const float* bee_f  = wptr[7];
  const float* Wpre_f = wptr[8];
  const float* bpre_f = wptr[9];
  const float* Wpost_f= wptr[10];
  const float* bpost_f= wptr[11];
  const float* Wlin_f = wptr[12];
  const float* blin_f = wptr[13];
  const float* bng_f  = wptr[14];
  const float* bnb_f  = wptr[15];
  const float* Wm0_f  = wptr[16];
  const float* bm0_f  = wptr[17];
  const float* Wmh_f  = wptr[18];
  const float* bmh_f  = wptr[19];
  const float* bnmg_f = wptr[20];
  const float* bnmb_f = wptr[21];
  const float* Wf_f   = wptr[22];
  const float* bf_f   = wptr[23];

  hipMemsetAsync(flags, 0, 64, stream);
  hipMemsetAsync(deg, 0, (size_t)NN*4, stream);
  hipMemsetAsync(cursor, 0, (size_t)NN*4, stream);

  k_detect<<<1, 256, 0, stream>>>((const u16*)d_in[4], flags);
  k_det_i64<<<NE/256, 256, 0, stream>>>((const int*)d_in[1], flags);
  k_set_i64<<<1, 1, 0, stream>>>(flags);
  k_cvt_int<<<(itotal+255)/256, 256, 0, stream>>>(ij, flags, itotal);
  k_cvt<<<(total+255)/256, 256, 0, stream>>>(jb, flags, total);

  k_count<<<NE/256, 256, 0, stream>>>(cei+NE, deg);
  k_scan<<<1, 256, 0, stream>>>(deg, offs);
  k_fill<<<NE/256, 256, 0, stream>>>(cei, cei+NE, cea, offs, cursor, esrc, eatt);
  k_logsumF<<<1, 256, 0, stream>>>(deg, lsum);
  k_scalersF<<<NN/256, 256, 0, stream>>>(deg, lsum, amp, attn, invc);
  k_embed<<<NN*FD/256, 256, 0, stream>>>(cx, ne_f, h);
  k_bounds<<<NN/256, 256, 0, stream>>>(cbatch, bstart);

  for (int l=0; l<NL; l++){
    k_eenc<<<2, 256, 0, stream>>>(ee_f, Wee_f, bee_f, eenc, l);
    k_etab2<<<16, 256, 0, stream>>>(eenc, Wpre_f, etab, l);
    k_pre<<<NN/64, 256, 0, stream>>>(h, Wpre_f, bpre_f, nbase, psrc, l);
    k_agg<<<NN/16, 1024, 0, stream>>>(nbase, psrc, etab, esrc, eatt, offs, h, amp, attn, invc,
                                      Wpost_f, bpost_f, Wlin_f, blin_f, z, l);
    hipMemsetAsync(st1, 0, 64*8, stream);
    k_stats2<<<64, 256, 0, stream>>>(z, st1);
    k_bnF<<<NN*FD/256, 256, 0, stream>>>(z, st1, bng_f, bnb_f, h, l);
  }

  k_pool2<<<NB, 256, 0, stream>>>(h, bstart, gp);
  k_head2<<<1, 512, 0, stream>>>(gp, Wm0_f, bm0_f, Wmh_f, bmh_f, bnmg_f, bnmb_f, Wf_f, bf_f, out);
}

// Round 11
// 448.001 us; speedup vs baseline: 15.0546x; 1.1420x over previous
//
#include <hip/hip_runtime.h>
#include <hip/hip_bf16.h>
#include <math.h>

#define NN 16384
#define NE 262144
#define NB 64
#define FD 32
#define NT 8
#define NL 3
#define NH 128
#define EPSV 1e-5f

typedef unsigned short u16;
typedef unsigned int u32;
typedef long long i64;

static __device__ __forceinline__ float us2f(u16 u){
  union { u32 i; float f; } z; z.i = ((u32)u) << 16; return z.f;
}
static __device__ __forceinline__ u16 f2us(float v){
  __hip_bfloat16 b = __float2bfloat16(v);
  return *(u16*)&b;
}

__global__ void k_diag(float* out, float v){
  int i = threadIdx.x;
  if (i < 128) out[i] = v;
}

// ---------- weight dtype detect ----------
__global__ __launch_bounds__(256) void k_detect(const u16* __restrict__ ne, int* __restrict__ flags){
  __shared__ float red[256];
  const int tid = threadIdx.x;
  float m = 0.f;
  for (int i=tid; i<1024; i+=256) m = fmaxf(m, fabsf(us2f(ne[i])));
  red[tid]=m; __syncthreads();
  for (int off=128; off>0; off>>=1){ if (tid<off) red[tid]=fmaxf(red[tid],red[tid+off]); __syncthreads(); }
  if (tid==0) flags[0] = (red[0] > 100.f) ? 1 : 0;
}

// ---------- int width detect ----------
__global__ __launch_bounds__(256) void k_det_i64(const int* __restrict__ ei_raw, int* __restrict__ flags){
  __shared__ int red[256];
  const int tid = threadIdx.x;
  int i = blockIdx.x*256 + tid;
  int c = (i < NE && ei_raw[2*i+1] == 0) ? 1 : 0;
  red[tid]=c; __syncthreads();
  for (int off=128; off>0; off>>=1){ if (tid<off) red[tid]+=red[tid+off]; __syncthreads(); }
  if (tid==0) atomicAdd(&flags[4], red[0]);
}

struct IJobs { const void* src[4]; int* dst[4]; int cnt[4]; };
__global__ __launch_bounds__(256) void k_cvt_int(IJobs jb, const int* __restrict__ flags, int total){
  int i = blockIdx.x*256 + threadIdx.x;
  if (i >= total) return;
  const int m = (flags[4] > NE/4) ? 1 : 0;
  int a = 0, off = i;
  while (off >= jb.cnt[a]){ off -= jb.cnt[a]; a++; }
  int v = m ? (int)((const i64*)jb.src[a])[off] : ((const int*)jb.src[a])[off];
  jb.dst[a][off] = v;
}

struct Jobs { const void* src[20]; float* dst[20]; int cnt[20]; };
__global__ __launch_bounds__(256) void k_cvt(Jobs jb, const int* __restrict__ flags, int total){
  int i = blockIdx.x*256 + threadIdx.x;
  if (i >= total) return;
  const int m = flags[0];
  int a = 0, off = i;
  while (off >= jb.cnt[a]){ off -= jb.cnt[a]; a++; }
  float v = m ? ((const float*)jb.src[a])[off]
              : us2f(((const u16*)jb.src[a])[off]);
  jb.dst[a][off] = v;
}

// ---------------- CSR build ----------------
__global__ void k_count(const int* __restrict__ dst, int* __restrict__ deg){
  int e = blockIdx.x*256 + threadIdx.x;
  if (e < NE) atomicAdd(&deg[dst[e]], 1);
}

__global__ __launch_bounds__(256) void k_scan(const int* __restrict__ deg, int* __restrict__ offs){
  __shared__ int part[257];
  const int tid = threadIdx.x;
  int s = 0;
  for (int i=0;i<64;i++) s += deg[tid*64+i];
  part[tid+1] = s;
  __syncthreads();
  if (tid==0){ part[0]=0; for (int i=1;i<=256;i++) part[i]+=part[i-1]; }
  __syncthreads();
  int run = part[tid];
  for (int i=0;i<64;i++){ offs[tid*64+i]=run; run+=deg[tid*64+i]; }
  if (tid==255) offs[NN]=run;
}

__global__ void k_fill(const int* __restrict__ src, const int* __restrict__ dst,
                       const int* __restrict__ ea_in, const int* __restrict__ offs,
                       int* __restrict__ cursor, int* __restrict__ esrc, int* __restrict__ eatt){
  int e = blockIdx.x*256 + threadIdx.x;
  if (e < NE){
    int d = dst[e];
    int pslot = atomicAdd(&cursor[d], 1);
    int idx = offs[d] + pslot;
    esrc[idx] = src[e];
    eatt[idx] = ea_in[e];
  }
}

// ---------------- avg log + scalers ----------------
__global__ __launch_bounds__(256) void k_logsumF(const int* __restrict__ deg, double* __restrict__ lsum){
  __shared__ double red[256];
  const int tid = threadIdx.x;
  double s = 0.0;
  for (int n=tid; n<NN; n+=256) s += log((double)deg[n] + 1.0);
  red[tid]=s; __syncthreads();
  for (int off=128; off>0; off>>=1){ if (tid<off) red[tid]+=red[tid+off]; __syncthreads(); }
  if (tid==0) *lsum = red[0] / (double)NN;
}

__global__ void k_scalersF(const int* __restrict__ deg, const double* __restrict__ lsum,
                           float* __restrict__ amp, float* __restrict__ attn, float* __restrict__ invc){
  int n = blockIdx.x*256 + threadIdx.x;
  if (n >= NN) return;
  float avg = (float)(*lsum);
  int d = deg[n]; int dc = d > 0 ? d : 1;
  float la = logf((float)dc + 1.0f);
  amp[n] = la/avg; attn[n] = avg/la; invc[n] = 1.0f/(float)dc;
}

// ---------------- embedding ----------------
__global__ void k_embed(const int* __restrict__ x, const float* __restrict__ emb,
                        float* __restrict__ h){
  int i = blockIdx.x*256 + threadIdx.x;
  if (i < NN*FD){
    int n = i>>5, f = i&31;
    h[i] = emb[x[n]*FD + f];
  }
}

// ---------------- fused eenc + etab ----------------
__global__ __launch_bounds__(256) void k_etab3(const float* __restrict__ ee, const float* __restrict__ Wee,
                      const float* __restrict__ bee, const float* __restrict__ Wpre,
                      float* __restrict__ etab, int l){
  __shared__ float el[16*FD];
  const int tid = threadIdx.x;
  for (int i=tid; i<16*FD; i+=256){
    int a = i>>5, f2 = i&31;
    float acc = bee[l*FD + f2];
    for (int c2=0; c2<16; c2++)
      acc = fmaf(ee[a*16+c2], Wee[(l*16+c2)*FD+f2], acc);
    el[i] = acc;
  }
  __syncthreads();
  int i = blockIdx.x*256 + tid;
  int a = i>>8, dd = i&255, t = dd>>5, f = dd&31;
  float acc = 0.f;
  for (int f2=0; f2<FD; f2++)
    acc = fmaf(el[a*FD+f2], Wpre[((l*NT+t)*96 + 64 + f2)*FD + f], acc);
  etab[i] = acc;
}

// ---------------- per-node pre: nbase f32, psrc bf16 ----------------
__global__ __launch_bounds__(256) void k_pre(const float* __restrict__ h,
                     const float* __restrict__ Wpre, const float* __restrict__ bpre,
                     float* __restrict__ nbase, u16* __restrict__ psrcH, int l){
  __shared__ float hl[64*FD];
  const int tid = threadIdx.x;
  const int t = tid>>5, f = tid&31;
  float wd[32], ws[32];
  #pragma unroll
  for (int c=0;c<FD;c++){
    wd[c] = Wpre[((l*NT+t)*96 + c)*FD + f];
    ws[c] = Wpre[((l*NT+t)*96 + 32 + c)*FD + f];
  }
  const float bb = bpre[(l*NT+t)*FD + f];
  const int n0 = blockIdx.x*64;
  for (int i=tid; i<64*FD; i+=256) hl[i] = h[n0*FD + i];
  __syncthreads();
  for (int nn=0; nn<64; nn++){
    float ad=bb, as=0.f;
    #pragma unroll
    for (int c=0;c<FD;c++){ float hv=hl[nn*FD+c]; ad=fmaf(hv,wd[c],ad); as=fmaf(hv,ws[c],as); }
    const int n = n0+nn;
    nbase[(size_t)n*256+tid]=ad;
    psrcH[(size_t)n*256+tid]=f2us(as);
  }
}

// ---------------- fused aggregation + post-MLP + Wlin ----------------
__global__ __launch_bounds__(1024) void k_agg(
    const float* __restrict__ nbase, const u16* __restrict__ psrcH,
    const float* __restrict__ etab,
    const int* __restrict__ esrc, const int* __restrict__ eatt, const int* __restrict__ offs,
    const float* __restrict__ h, const float* __restrict__ amp,
    const float* __restrict__ attn, const float* __restrict__ invc,
    const float* __restrict__ Wpost, const float* __restrict__ bpost,
    const float* __restrict__ Wlin, const float* __restrict__ blin,
    float* __restrict__ z, int l)
{
  __shared__ u16 wp[13312];
  __shared__ float wl[1024];
  __shared__ float bpo[32], bli[32];
  const int tid = threadIdx.x;
  const float* WpL = Wpost + (size_t)l*13312;
  for (int i=tid;i<13312;i+=1024) wp[i] = (u16)(__float_as_uint(WpL[i])>>16);
  if (tid < 1024) wl[tid] = Wlin[l*1024+tid];
  if (tid<32){ bpo[tid]=bpost[l*32+tid]; bli[tid]=blin[l*32+tid]; }
  __syncthreads();
  const int wid = tid>>6, lane = tid&63;
  const int t = lane>>3, q = lane&7;
  const int n = blockIdx.x*16 + wid;
  const int o0 = offs[n], o1 = offs[n+1];
  float bs[4]; *(float4*)bs = *(const float4*)(nbase + (size_t)n*256 + lane*4);
  float sum[4]={0,0,0,0}, sq[4]={0,0,0,0}, mn[4], mx[4];
  #pragma unroll
  for (int k=0;k<4;k++){ mn[k]=__builtin_inff(); mx[k]=-__builtin_inff(); }
  int j = o0;
  for (; j+3 < o1; j+=4){
    const int s0=esrc[j],   s1=esrc[j+1], s2=esrc[j+2], s3=esrc[j+3];
    const int a0=eatt[j],   a1=eatt[j+1], a2=eatt[j+2], a3=eatt[j+3];
    ushort4 p0 = *(const ushort4*)(psrcH + (size_t)s0*256 + lane*4);
    ushort4 p1 = *(const ushort4*)(psrcH + (size_t)s1*256 + lane*4);
    ushort4 p2 = *(const ushort4*)(psrcH + (size_t)s2*256 + lane*4);
    ushort4 p3 = *(const ushort4*)(psrcH + (size_t)s3*256 + lane*4);
    float4 e0 = *(const float4*)(etab + a0*256 + lane*4);
    float4 e1 = *(const float4*)(etab + a1*256 + lane*4);
    float4 e2 = *(const float4*)(etab + a2*256 + lane*4);
    float4 e3 = *(const float4*)(etab + a3*256 + lane*4);
    const u16* pp0=(const u16*)&p0; const float* ee0=(const float*)&e0;
    const u16* pp1=(const u16*)&p1; const float* ee1=(const float*)&e1;
    const u16* pp2=(const u16*)&p2; const float* ee2=(const float*)&e2;
    const u16* pp3=(const u16*)&p3; const float* ee3=(const float*)&e3;
    #pragma unroll
    for (int k=0;k<4;k++){
      float v0 = bs[k] + us2f(pp0[k]) + ee0[k];
      float v1 = bs[k] + us2f(pp1[k]) + ee1[k];
      float v2 = bs[k] + us2f(pp2[k]) + ee2[k];
      float v3 = bs[k] + us2f(pp3[k]) + ee3[k];
      sum[k] += (v0+v1)+(v2+v3);
      sq[k] = fmaf(v0,v0,sq[k]); sq[k] = fmaf(v1,v1,sq[k]);
      sq[k] = fmaf(v2,v2,sq[k]); sq[k] = fmaf(v3,v3,sq[k]);
      mn[k] = fminf(mn[k], fminf(fminf(v0,v1), fminf(v2,v3)));
      mx[k] = fmaxf(mx[k], fmaxf(fmaxf(v0,v1), fmaxf(v2,v3)));
    }
  }
  for (; j < o1; j++){
    const int s = esrc[j];
    const int a = eatt[j];
    ushort4 pv4 = *(const ushort4*)(psrcH + (size_t)s*256 + lane*4);
    float4 ev4 = *(const float4*)(etab + a*256 + lane*4);
    const u16* pv=(const u16*)&pv4; const float* ev=(const float*)&ev4;
    #pragma unroll
    for (int k=0;k<4;k++){
      float v = bs[k] + us2f(pv[k]) + ev[k];
      sum[k]+=v; sq[k]=fmaf(v,v,sq[k]); mn[k]=fminf(mn[k],v); mx[k]=fmaxf(mx[k],v);
    }
  }
  const int dg = o1-o0;
  const float ic = invc[n];
  float aggv[4][4];
  #pragma unroll
  for (int k=0;k<4;k++){
    float mean = sum[k]*ic;
    float ms = sq[k]*ic;
    float var = fmaxf(ms - mean*mean, 0.f);
    aggv[0][k]=mean;
    aggv[1][k]=(dg>0)?mn[k]:0.f;
    aggv[2][k]=(dg>0)?mx[k]:0.f;
    aggv[3][k]=sqrtf(var+EPSV);
  }
  const float av = amp[n], at_ = attn[n];
  float acc[4]={0,0,0,0};
  float hv[4]; *(float4*)hv = *(const float4*)(h + n*FD + q*4);
  #pragma unroll
  for (int k=0;k<4;k++){
    int c = q*4+k;
    #pragma unroll
    for (int jj=0;jj<4;jj++)
      acc[jj] = fmaf(hv[k], us2f(wp[(t*416+c)*4+jj]), acc[jj]);
  }
  #pragma unroll
  for (int g=0; g<4; g++){
    #pragma unroll
    for (int k=0;k<4;k++){
      float a_ = aggv[g][k];
      int rb = 32 + g*32 + q*4 + k;
      #pragma unroll
      for (int jj=0;jj<4;jj++){
        float w = us2f(wp[(t*416+rb)*4+jj])
                + av*us2f(wp[(t*416+rb+128)*4+jj])
                + at_*us2f(wp[(t*416+rb+256)*4+jj]);
        acc[jj] = fmaf(a_, w, acc[jj]);
      }
    }
  }
  #pragma unroll
  for (int jj=0;jj<4;jj++){
    acc[jj] += __shfl_xor(acc[jj], 1);
    acc[jj] += __shfl_xor(acc[jj], 2);
    acc[jj] += __shfl_xor(acc[jj], 4);
    acc[jj] += bpo[t*4+jj];
  }
  float zv = 0.f;
  #pragma unroll
  for (int dp=0; dp<32; dp++){
    float v = __shfl(acc[dp&3], (dp>>2)*8);
    zv = fmaf(v, wl[dp*32 + (lane&31)], zv);
  }
  if (lane < 32) z[n*FD + lane] = zv + bli[lane];
}

// ---------------- BN: single-pass f64 sum+sumsq ----------------
__global__ __launch_bounds__(256) void k_stats2(const float* __restrict__ z, double* __restrict__ st){
  const int tid = threadIdx.x;
  const int f = tid&31, rg = tid>>5;
  double s1=0.0, s2=0.0;
  for (int n = blockIdx.x*8 + rg; n < NN; n += 512){
    double v = (double)z[n*FD+f]; s1 += v; s2 += v*v;
  }
  __shared__ double l1[256], l2[256];
  l1[tid]=s1; l2[tid]=s2; __syncthreads();
  if (rg<4){ l1[tid]+=l1[tid+128]; l2[tid]+=l2[tid+128]; } __syncthreads();
  if (rg<2){ l1[tid]+=l1[tid+64];  l2[tid]+=l2[tid+64];  } __syncthreads();
  if (rg<1){
    atomicAdd(&st[f],    l1[tid]+l1[tid+32]);
    atomicAdd(&st[32+f], l2[tid]+l2[tid+32]);
  }
}
__global__ void k_bnF(const float* __restrict__ z, const double* __restrict__ st,
                      const float* __restrict__ bng, const float* __restrict__ bnb,
                      float* __restrict__ h, int l){
  int i = blockIdx.x*256 + threadIdx.x;
  if (i >= NN*FD) return;
  int f = i&31;
  double mu = st[f] * (1.0/(double)NN);
  double var = st[32+f] * (1.0/(double)NN) - mu*mu;
  float varf = fmaxf((float)var, 0.f);
  float sc = bng[l*FD+f]*rsqrtf(varf+EPSV);
  float v = (z[i]-(float)mu)*sc + bnb[l*FD+f];
  h[i] = fmaxf(v, 0.f);
}

// ---------------- pooling: segmented ----------------
__global__ __launch_bounds__(256) void k_bounds(const int* __restrict__ batch, int* __restrict__ bstart){
  int n = blockIdx.x*256 + threadIdx.x;
  if (n >= NN) return;
  int b = batch[n];
  int prev = (n==0) ? -1 : batch[n-1];
  for (int v=prev+1; v<=b; v++) bstart[v]=n;
  if (n==NN-1) for (int v=b+1; v<=NB; v++) bstart[v]=NN;
}
__global__ __launch_bounds__(256) void k_pool2(const float* __restrict__ h, const int* __restrict__ bstart,
                                               float* __restrict__ g){
  __shared__ float acc[8][FD];
  const int b = blockIdx.x;
  const int tid = threadIdx.x;
  const int f = tid&31, rg = tid>>5;
  const int lo = bstart[b], hi = bstart[b+1];
  float s = 0.f;
  for (int n=lo+rg; n<hi; n+=8) s += h[n*FD+f];
  acc[rg][f] = s; __syncthreads();
  if (rg == 0){
    float t = 0.f;
    for (int r=0;r<8;r++) t += acc[r][f];
    g[b*FD+f] = t;
  }
}

// ---------------- head: grid-parallel kernels ----------------
__global__ __launch_bounds__(256) void k_hgemm(const float* __restrict__ in, const float* __restrict__ W,
                                               const float* __restrict__ bias, float* __restrict__ outp,
                                               int IN){
  int o = blockIdx.x*256 + threadIdx.x;   // 8192
  int b = o>>7, hh = o&127;
  float acc = bias[hh];
  for (int c=0;c<IN;c++) acc = fmaf(in[b*IN+c], W[c*NH+hh], acc);
  outp[o] = acc;
}

__global__ __launch_bounds__(512) void k_hbn(float* __restrict__ buf,
                                             const float* __restrict__ gvec, const float* __restrict__ bvec){
  __shared__ float scf[NH], shf[NH];
  const int tid = threadIdx.x;
  const int f = tid>>2, part = tid&3;
  double s1=0.0, s2=0.0;
  for (int b=part*16; b<part*16+16; b++){
    double v = (double)buf[b*NH+f]; s1+=v; s2+=v*v;
  }
  s1 += __shfl_xor(s1, 1); s2 += __shfl_xor(s2, 1);
  s1 += __shfl_xor(s1, 2); s2 += __shfl_xor(s2, 2);
  if (part==0){
    double mu = s1/(double)NB;
    double var = s2/(double)NB - mu*mu;
    float varf = fmaxf((float)var, 0.f);
    float sc = gvec[f]*rsqrtf(varf+EPSV);
    scf[f]=sc; shf[f]=bvec[f]-(float)mu*sc;
  }
  __syncthreads();
  for (int i=tid; i<NB*NH; i+=512){
    int hh = i&127;
    buf[i] = fmaxf(buf[i]*scf[hh]+shf[hh], 0.f);
  }
}

__global__ __launch_bounds__(64) void k_hfin(const float* __restrict__ buf, const float* __restrict__ Wf,
                                             const float* __restrict__ bfv, float* __restrict__ out){
  int b = threadIdx.x;
  float acc = bfv[0];
  for (int c=0;c<NH;c++) acc = fmaf(buf[b*NH+c], Wf[c], acc);
  out[NB+b] = acc;
  out[b]    = 1.f/(1.f+expf(-acc));
}

extern "C" void kernel_launch(void* const* d_in, const int* in_sizes, int n_in,
                              void* d_out, int out_size, void* d_ws, size_t ws_size,
                              hipStream_t stream)
{
  float* out = (float*)d_out;

  static const int EXP_SZ[24] = {16384, 524288, 262144, 16384, 1024, 256, 1536, 96,
                                 73728, 768, 39936, 96, 3072, 96, 96, 96,
                                 4096, 128, 32768, 256, 384, 384, 128, 1};
  int bad = -1;
  if (n_in != 24) bad = 24;
  else for (int i=0;i<24;i++){ if (in_sizes[i] != EXP_SZ[i]){ bad = i; break; } }
  if (bad >= 0){
    k_diag<<<1, 128, 0, stream>>>(out, 512.0f + 8.0f*(float)bad);
    return;
  }

  char* p = (char*)d_ws;
  auto carve = [&](size_t bytes)->char*{ char* r = p; p += (bytes + 255) & ~(size_t)255; return r; };
  int*    flags = (int*)carve(64);
  int*    deg   = (int*)carve((size_t)NN*4);
  int*    cursor= (int*)carve((size_t)NN*4);
  int*    offs  = (int*)carve((size_t)(NN+1)*4);
  int*    esrc  = (int*)carve((size_t)NE*4);
  int*    eatt  = (int*)carve((size_t)NE*4);
  int*    bstart= (int*)carve((size_t)(NB+1)*4);
  float*  h     = (float*)carve((size_t)NN*FD*4);
  float*  z     = (float*)carve((size_t)NN*FD*4);
  float*  nbase = (float*)carve((size_t)NN*256*4);
  u16*    psrcH = (u16*)carve((size_t)NN*256*2);
  float*  etab  = (float*)carve(4096*4);
  float*  amp   = (float*)carve((size_t)NN*4);
  float*  attn  = (float*)carve((size_t)NN*4);
  float*  invc  = (float*)carve((size_t)NN*4);
  double* lsum  = (double*)carve(8);
  double* st1   = (double*)carve(64*8);
  float*  gp    = (float*)carve((size_t)NB*FD*4);
  float*  t0    = (float*)carve((size_t)NB*NH*4);
  float*  t1    = (float*)carve((size_t)NB*NH*4);
  float*  t2    = (float*)carve((size_t)NB*NH*4);
  int*    cx    = (int*)carve((size_t)NN*4);
  int*    cei   = (int*)carve((size_t)2*NE*4);
  int*    cea   = (int*)carve((size_t)NE*4);
  int*    cbatch= (int*)carve((size_t)NN*4);

  Jobs jb;
  float* wptr[24];
  int total = 0;
  {
    float* cur = (float*)carve(700*1024);
    for (int i=4; i<24; i++){
      jb.src[i-4] = d_in[i];
      jb.dst[i-4] = cur;
      jb.cnt[i-4] = in_sizes[i];
      wptr[i] = cur;
      cur += in_sizes[i];
      total += in_sizes[i];
    }
  }
  const size_t need = (size_t)(p - (char*)d_ws);
  if (ws_size < need){
    k_diag<<<1, 128, 0, stream>>>(out, -2000.0f - (float)(ws_size >> 20));
    return;
  }

  IJobs ij;
  ij.src[0]=d_in[0]; ij.dst[0]=cx;     ij.cnt[0]=NN;
  ij.src[1]=d_in[1]; ij.dst[1]=cei;    ij.cnt[1]=2*NE;
  ij.src[2]=d_in[2]; ij.dst[2]=cea;    ij.cnt[2]=NE;
  ij.src[3]=d_in[3]; ij.dst[3]=cbatch; ij.cnt[3]=NN;
  const int itotal = NN + 2*NE + NE + NN;

  const float* ne_f   = wptr[4];
  const float* ee_f   = wptr[5];
  const float* Wee_f  = wptr[6];
  const float* bee_f  = wptr[7];
  const float* Wpre_f = wptr[8];
  const float* bpre_f = wptr[9];
  const float* Wpost_f= wptr[10];
  const float* bpost_f= wptr[11];
  const float* Wlin_f = wptr[12];
  const float* blin_f = wptr[13];
  const float* bng_f  = wptr[14];
  const float* bnb_f  = wptr[15];
  const float* Wm0_f  = wptr[16];
  const float* bm0_f  = wptr[17];
  const float* Wmh_f  = wptr[18];
  const float* bmh_f  = wptr[19];
  const float* bnmg_f = wptr[20];
  const float* bnmb_f = wptr[21];
  const float* Wf_f   = wptr[22];
  const float* bf_f   = wptr[23];

  hipMemsetAsync(flags, 0, 64, stream);
  hipMemsetAsync(deg, 0, (size_t)NN*4, stream);
  hipMemsetAsync(cursor, 0, (size_t)NN*4, stream);

  k_detect<<<1, 256, 0, stream>>>((const u16*)d_in[4], flags);
  k_det_i64<<<NE/256, 256, 0, stream>>>((const int*)d_in[1], flags);
  k_cvt_int<<<(itotal+255)/256, 256, 0, stream>>>(ij, flags, itotal);
  k_cvt<<<(total+255)/256, 256, 0, stream>>>(jb, flags, total);

  k_count<<<NE/256, 256, 0, stream>>>(cei+NE, deg);
  k_scan<<<1, 256, 0, stream>>>(deg, offs);
  k_fill<<<NE/256, 256, 0, stream>>>(cei, cei+NE, cea, offs, cursor, esrc, eatt);
  k_logsumF<<<1, 256, 0, stream>>>(deg, lsum);
  k_scalersF<<<NN/256, 256, 0, stream>>>(deg, lsum, amp, attn, invc);
  k_embed<<<NN*FD/256, 256, 0, stream>>>(cx, ne_f, h);
  k_bounds<<<NN/256, 256, 0, stream>>>(cbatch, bstart);

  for (int l=0; l<NL; l++){
    k_etab3<<<16, 256, 0, stream>>>(ee_f, Wee_f, bee_f, Wpre_f, etab, l);
    k_pre<<<NN/64, 256, 0, stream>>>(h, Wpre_f, bpre_f, nbase, psrcH, l);
    k_agg<<<NN/16, 1024, 0, stream>>>(nbase, psrcH, etab, esrc, eatt, offs, h, amp, attn, invc,
                                      Wpost_f, bpost_f, Wlin_f, blin_f, z, l);
    hipMemsetAsync(st1, 0, 64*8, stream);
    k_stats2<<<64, 256, 0, stream>>>(z, st1);
    k_bnF<<<NN*FD/256, 256, 0, stream>>>(z, st1, bng_f, bnb_f, h, l);
  }

  k_pool2<<<NB, 256, 0, stream>>>(h, bstart, gp);
  k_hgemm<<<32, 256, 0, stream>>>(gp, Wm0_f, bm0_f, t0, FD);
  k_hbn<<<1, 512, 0, stream>>>(t0, bnmg_f, bnmb_f);
  k_hgemm<<<32, 256, 0, stream>>>(t0, Wmh_f, bmh_f, t1, NH);
  k_hbn<<<1, 512, 0, stream>>>(t1, bnmg_f+NH, bnmb_f+NH);
  k_hgemm<<<32, 256, 0, stream>>>(t1, Wmh_f+NH*NH, bmh_f+NH, t2, NH);
  k_hbn<<<1, 512, 0, stream>>>(t2, bnmg_f+2*NH, bnmb_f+2*NH);
  k_hfin<<<1, 64, 0, stream>>>(t2, Wf_f, bf_f, out);
}